// Round 6
// baseline (348.641 us; speedup 1.0000x reference)
//
#include <hip/hip_runtime.h>
#include <math.h>

typedef float f32x4 __attribute__((ext_vector_type(4)));
typedef short s16x8 __attribute__((ext_vector_type(8)));
typedef unsigned short u16x8 __attribute__((ext_vector_type(8)));
typedef unsigned short ushort_t;
typedef unsigned int uint_t;

#define D_MODEL 512
#define N_HEADS 8
#define HEAD_D  64
#define D_FFN   2048

__device__ __forceinline__ float bf2f(unsigned short u) {
  union { unsigned int i; float f; } c; c.i = ((unsigned int)u) << 16; return c.f;
}
__device__ __forceinline__ unsigned short f2bf(float f) {
  union { float f; unsigned int i; } c; c.f = f;
  unsigned int x = c.i;
  return (unsigned short)((x + 0x7FFFu + ((x >> 16) & 1u)) >> 16);
}
__device__ __forceinline__ float ldx(const void* p, size_t i, int f) {
  return f ? ((const float*)p)[i] : bf2f(((const ushort_t*)p)[i]);
}

// ------------------------------------------------- fused dtype detector
// One tiny upfront kernel; every consumer pays a single scalar flags[] load.
// (R1/R2 lesson: per-block inline probes cost ~13 µs of tail latency.)
struct DetectArgs { const void* p[14]; int n[14]; };

__global__ __launch_bounds__(256)
void detect_all(DetectArgs a, int* __restrict__ flags) {
  __shared__ int cnt[2];
  const int b = blockIdx.x;
  const int t = threadIdx.x;
  if (b == 0 && t == 64) flags[14] = 1;   // constant "f32" flag for fused b1'
  if (b == 1) { if (t == 0) flags[1] = 0; return; }
  if (t == 0) { cnt[0] = 0; cnt[1] = 0; }
  __syncthreads();
  const int n_u32 = a.n[b] >> 1;
  const int sample = n_u32 < 256 ? n_u32 : 256;
  if (t < sample) {
    uint_t u = ((const uint_t*)a.p[b])[t];
    if (u != 0u) {
      atomicAdd(&cnt[0], 1);
      int e = (u >> 7) & 0xFF;
      if (e >= 0x70 && e <= 0x83) atomicAdd(&cnt[1], 1);
    }
  }
  __syncthreads();
  if (t == 0) flags[b] = (cnt[0] >= 32 && cnt[1] * 4 <= cnt[0]) ? 1 : 0;
}

// ------------------------------------------------- prep: wconv + ln1 + ln2-fold
// R6: LN2 algebraic fold. (x_hat*g + b) @ w1 == x_hat @ (g(*)w1) + (b.w1).
//  - w1 conversion scales row k by ln2_g[k] (when fusing).
//  - 8 extra blocks compute b1p[n] = b1[n] + sum_k ln2_b[k]*w1[k][n] (f32)
//    and zero the per-row stats buffer. Hidden under prep's 3.5k-block TLP.
struct WDesc { const void* src; ushort_t* dst; int Kd, Nd, flag, tile0; };

__global__ __launch_bounds__(256)
void prep_kernel(WDesc w0, WDesc w1, WDesc w2, WDesc w3, int nconv, int nln,
                 const void* __restrict__ x, const void* __restrict__ g,
                 const void* __restrict__ b, ushort_t* __restrict__ h1,
                 const void* __restrict__ g2, const void* __restrict__ b2,
                 const void* __restrict__ w1src, const void* __restrict__ b1src,
                 float* __restrict__ b1p, float* __restrict__ stats,
                 const int* __restrict__ flags) {
  __shared__ ushort_t tile[32][33];
  const int blk = blockIdx.x;
  const int t = threadIdx.x;
  if (blk >= nconv + nln) {
    // ----- ln2-fold matvec + stats zero (only launched when fused)
    const int mb = blk - nconv - nln;
    const int n = mb * 256 + t;
    stats[n * 2] = 0.f; stats[n * 2 + 1] = 0.f;   // 2048 rows x {sum,sq}
    const int fw1 = flags[10], fb2 = flags[5], fb1 = flags[11];
    float acc = ldx(b1src, n, fb1);
#pragma unroll 8
    for (int k = 0; k < D_MODEL; ++k)
      acc += ldx(b2, k, fb2) * ldx(w1src, (size_t)k * D_FFN + n, fw1);
    b1p[n] = acc;
    return;
  }
  if (blk >= nconv) {
    // ----- ln1 path (4 rows per block)
    const int fx = flags[0], fg = flags[2], fb = flags[3];
    const int row = (blk - nconv) * 4 + (t >> 6);
    const int lane = t & 63;
    float v[8], sum = 0.f, sq = 0.f;
#pragma unroll
    for (int i = 0; i < 8; ++i) {
      v[i] = ldx(x, (size_t)row * D_MODEL + lane * 8 + i, fx);
      sum += v[i]; sq += v[i] * v[i];
    }
#pragma unroll
    for (int o = 32; o > 0; o >>= 1) { sum += __shfl_xor(sum, o); sq += __shfl_xor(sq, o); }
    const float mu = sum * (1.0f / D_MODEL);
    const float var = sq * (1.0f / D_MODEL) - mu * mu;
    const float rstd = rsqrtf(var + 1e-5f);
#pragma unroll
    for (int i = 0; i < 8; ++i) {
      int c = lane * 8 + i;
      h1[(size_t)row * D_MODEL + c] =
          f2bf((v[i] - mu) * rstd * ldx(g, c, fg) + ldx(b, c, fb));
    }
    return;
  }
  // ----- weight convert+transpose path
  WDesc d = (blk < w1.tile0) ? w0 : (blk < w2.tile0) ? w1 : (blk < w3.tile0) ? w2 : w3;
  const int lt = blk - d.tile0;
  const int tn = d.Nd / 32;
  const int bk = lt / tn, bn = lt % tn;
  const int f = flags[d.flag];
  const int scale_w1 = (d.flag == 10 && b1p != nullptr);
  const int fg2 = flags[4];
  const int tx = t & 31, ty = t >> 5;
#pragma unroll
  for (int r = 0; r < 4; ++r) {
    int k = bk * 32 + ty * 4 + r;
    float val = ldx(d.src, (size_t)k * d.Nd + bn * 32 + tx, f);
    if (scale_w1) val *= ldx(g2, k, fg2);
    tile[ty * 4 + r][tx] = f2bf(val);
  }
  __syncthreads();
#pragma unroll
  for (int r = 0; r < 4; ++r) {
    int n = bn * 32 + ty * 4 + r;
    d.dst[(size_t)n * d.Kd + bk * 32 + tx] = tile[tx][ty * 4 + r];
  }
}

// ------------------------------------------------- LN kernels
__global__ __launch_bounds__(256)
void ln1_kernel(const void* __restrict__ x, const void* __restrict__ g,
                const void* __restrict__ b, ushort_t* __restrict__ out,
                const int* __restrict__ flags) {
  const int fx = flags[0], fg = flags[2], fb = flags[3];
  const int row = blockIdx.x * 4 + (threadIdx.x >> 6);
  const int lane = threadIdx.x & 63;
  float v[8], sum = 0.f, sq = 0.f;
#pragma unroll
  for (int i = 0; i < 8; ++i) {
    v[i] = ldx(x, (size_t)row * D_MODEL + lane * 8 + i, fx);
    sum += v[i]; sq += v[i] * v[i];
  }
#pragma unroll
  for (int o = 32; o > 0; o >>= 1) { sum += __shfl_xor(sum, o); sq += __shfl_xor(sq, o); }
  const float mu = sum * (1.0f / D_MODEL);
  const float var = sq * (1.0f / D_MODEL) - mu * mu;
  const float rstd = rsqrtf(var + 1e-5f);
#pragma unroll
  for (int i = 0; i < 8; ++i) {
    int c = lane * 8 + i;
    out[(size_t)row * D_MODEL + c] =
        f2bf((v[i] - mu) * rstd * ldx(g, c, fg) + ldx(b, c, fb));
  }
}

__global__ __launch_bounds__(256)
void ln2_kernel(const float* __restrict__ y, const void* __restrict__ g,
                const void* __restrict__ b, ushort_t* __restrict__ out,
                const int* __restrict__ flags) {
  const int fg = flags[4], fb = flags[5];
  const int row = blockIdx.x * 4 + (threadIdx.x >> 6);
  const int lane = threadIdx.x & 63;
  float v[8], sum = 0.f, sq = 0.f;
#pragma unroll
  for (int i = 0; i < 8; ++i) {
    v[i] = y[(size_t)row * D_MODEL + lane * 8 + i];
    sum += v[i]; sq += v[i] * v[i];
  }
#pragma unroll
  for (int o = 32; o > 0; o >>= 1) { sum += __shfl_xor(sum, o); sq += __shfl_xor(sq, o); }
  const float mu = sum * (1.0f / D_MODEL);
  const float var = sq * (1.0f / D_MODEL) - mu * mu;
  const float rstd = rsqrtf(var + 1e-5f);
#pragma unroll
  for (int i = 0; i < 8; ++i) {
    int c = lane * 8 + i;
    out[(size_t)row * D_MODEL + c] =
        f2bf((v[i] - mu) * rstd * ldx(g, c, fg) + ldx(b, c, fb));
  }
}

// ------------------------------------------------- pipelined MFMA GEMM, BK=64
// R5 write-early dbuf (proven): loads issued one full K-step ahead of their
// swrite; swizzled granules ((k>>3)^(row&7)); ONE barrier per K-step; 24 KB
// LDS -> 6 blocks/CU for 32x64.
// R6 adds:
//  - LNA: A operand is f32 y, normalized on-the-fly in staging using per-row
//    {sum,sq} stats (computed by gemm2's epilogue). Conversion VALU sits at
//    the latency-covered swrite point. (ln2 fold; requires BM==32.)
//  - EPI==2 + stats_out: epilogue 16-lane-reduces each output row slice and
//    atomically accumulates {sum, sum^2} for the LNA consumer.
// EPI: 0 = +bias -> bf16            1 = gelu(+bias) -> bf16
//      2 = y[off] = v+bias+res      3 = y[off] += v (+bias if addb)
//      4 = out[off] = y[off] + v (+bias if addb; dtype per flags[ires])
template <int BM, int BN, int EPI, int LNA>
__global__ __launch_bounds__(256)
void gemm_bt(const ushort_t* __restrict__ A, int lda,
             const ushort_t* __restrict__ BT, int ldb, int K,
             const void* __restrict__ bias, int bias_off,
             const void* __restrict__ res,
             float* __restrict__ yacc,
             ushort_t* __restrict__ out_bf, int ldo,
             const int* __restrict__ flags, int ibias, int ires, int addb,
             const float* __restrict__ af32, const float* __restrict__ stats,
             float* __restrict__ stats_out) {
  constexpr int BK = 64;
  constexpr int FM = BM / 32, FN = BN / 32;
  constexpr int AG = BM / 32, BG = BN / 32;   // staging groups of 32 rows
  static_assert(!LNA || BM == 32, "LNA staging assumes AG==1");
  __shared__ __attribute__((aligned(16))) ushort_t As[2][BM][64];
  __shared__ __attribute__((aligned(16))) ushort_t Bs[2][BN][64];

  const int t = threadIdx.x;
  const int lane = t & 63, wave = t >> 6;
  const int wm = wave >> 1, wn = wave & 1;
  const int q = lane >> 4, lm = lane & 15;
  const int m0 = blockIdx.y * BM, n0 = blockIdx.x * BN;
  const int srow = t >> 3, sslot = t & 7;   // 32 rows x 8 granules per pass
  const int wslot = (sslot ^ (srow & 7)) * 8;  // swizzled write column
  const int xorg = lm & 7;                   // fragment-read swizzle

  f32x4 acc[FM][FN];
#pragma unroll
  for (int i = 0; i < FM; ++i)
#pragma unroll
    for (int j = 0; j < FN; ++j) acc[i][j] = (f32x4)(0.0f);

  u16x8 av[AG], bv[BG];
  f32x4 avf0, avf1; float2 sst;

  auto gload = [&](int k0) {
    if constexpr (LNA) {
      const float* yr = af32 + (size_t)(m0 + srow) * lda + k0 + sslot * 8;
      avf0 = *(const f32x4*)yr;
      avf1 = *(const f32x4*)(yr + 4);
      sst = *(const float2*)&stats[(m0 + srow) * 2];
    } else {
#pragma unroll
      for (int r = 0; r < AG; ++r)
        av[r] = *(const u16x8*)(A + (size_t)(m0 + r * 32 + srow) * lda + k0 + sslot * 8);
    }
#pragma unroll
    for (int r = 0; r < BG; ++r)
      bv[r] = *(const u16x8*)(BT + (size_t)(n0 + r * 32 + srow) * ldb + k0 + sslot * 8);
  };
  auto swrite = [&](int buf) {
    if constexpr (LNA) {
      const float mu = sst.x * (1.0f / D_MODEL);
      const float rstd = rsqrtf(sst.y * (1.0f / D_MODEL) - mu * mu + 1e-5f);
      u16x8 w;
#pragma unroll
      for (int e = 0; e < 4; ++e) {
        w[e]     = f2bf((avf0[e] - mu) * rstd);
        w[e + 4] = f2bf((avf1[e] - mu) * rstd);
      }
      *(u16x8*)&As[buf][srow][wslot] = w;
    } else {
#pragma unroll
      for (int r = 0; r < AG; ++r) *(u16x8*)&As[buf][r * 32 + srow][wslot] = av[r];
    }
#pragma unroll
    for (int r = 0; r < BG; ++r) *(u16x8*)&Bs[buf][r * 32 + srow][wslot] = bv[r];
  };
  auto frag_mfma = [&](int buf, int kh) {
    s16x8 af[FM], bf[FN];
    const int rcol = ((kh * 4 + q) ^ xorg) * 8;   // swizzled read column
#pragma unroll
    for (int i = 0; i < FM; ++i)
      af[i] = *(const s16x8*)&As[buf][wm * (BM / 2) + i * 16 + lm][rcol];
#pragma unroll
    for (int j = 0; j < FN; ++j)
      bf[j] = *(const s16x8*)&Bs[buf][wn * (BN / 2) + j * 16 + lm][rcol];
#pragma unroll
    for (int i = 0; i < FM; ++i)
#pragma unroll
      for (int j = 0; j < FN; ++j)
        acc[i][j] = __builtin_amdgcn_mfma_f32_16x16x32_bf16(af[i], bf[j], acc[i][j], 0, 0, 0);
  };

  const int NT = K / BK;
  gload(0);
  swrite(0);            // exposed vmcnt once (prologue only)
  __syncthreads();
  gload(BK);            // tile 1 in flight across the whole first K-step
  int buf = 0;
  for (int kt = 1; kt < NT; ++kt) {
    swrite(buf ^ 1);    // stage tile kt (issued last iteration: latency covered)
    if (kt + 1 < NT) gload((kt + 1) * BK);   // issue tile kt+1
    frag_mfma(buf, 0);  // compute tile kt-1
    frag_mfma(buf, 1);
    __syncthreads();    // ONE barrier per K-step
    buf ^= 1;
  }
  frag_mfma(buf, 0);    // compute tile NT-1
  frag_mfma(buf, 1);

  const int fbias = flags[ibias];
  float yv[4] = {0.f, 0.f, 0.f, 0.f};
#pragma unroll
  for (int i = 0; i < FM; ++i) {
#pragma unroll
    for (int j = 0; j < FN; ++j) {
      const int colg = n0 + wn * (BN / 2) + j * 16 + lm;
      float bb = 0.0f;
      if (EPI <= 2 || addb) bb = ldx(bias, bias_off + colg, fbias);
#pragma unroll
      for (int r = 0; r < 4; ++r) {
        const int rowg = m0 + wm * (BM / 2) + i * 16 + q * 4 + r;
        float v = acc[i][j][r] + bb;
        const size_t off = (size_t)rowg * ldo + colg;
        if constexpr (EPI == 0) {
          out_bf[off] = f2bf(v);
        } else if constexpr (EPI == 1) {
          out_bf[off] = f2bf(0.5f * v * (1.0f + erff(v * 0.70710678f)));
        } else if constexpr (EPI == 2) {
          float fin = v + ldx(res, off, flags[ires]);
          yacc[off] = fin;
          yv[r] = fin;
        } else if constexpr (EPI == 3) {
          yacc[off] += v;
        } else {
          float fin = yacc[off] + v;
          if (flags[ires]) ((float*)(void*)out_bf)[off] = fin;
          else             out_bf[off] = f2bf(fin);
        }
      }
    }
  }
  if constexpr (EPI == 2) {
    static_assert(EPI != 2 || (FM == 1 && FN == 1), "stats path assumes 32x32");
    if (stats_out) {
#pragma unroll
      for (int r = 0; r < 4; ++r) {
        float s1 = yv[r], s2 = yv[r] * yv[r];
#pragma unroll
        for (int m = 1; m <= 8; m <<= 1) { s1 += __shfl_xor(s1, m); s2 += __shfl_xor(s2, m); }
        if (lm == 0) {
          const int row = m0 + wm * 16 + q * 4 + r;
          atomicAdd(&stats_out[row * 2], s1);
          atomicAdd(&stats_out[row * 2 + 1], s2);
        }
      }
    }
  }
}

// ------------------------------------------------- legacy GEMM (fallback path, r6-proven)
template <int BM, int BN, int EPI>
__global__ __launch_bounds__(256)
void gemm_nn(const ushort_t* __restrict__ A, int lda, int K,
             const void* __restrict__ B, int ldb, int brow0, int bcol0,
             const void* __restrict__ bias, int bias_off,
             const void* __restrict__ res,
             float* __restrict__ yacc,
             ushort_t* __restrict__ out_bf, int ldo,
             const int* __restrict__ flags, int iB, int ibias, int ires, int addb) {
  constexpr int BK = 32;
  constexpr int FM = BM / 32, FN = BN / 32;
  __shared__ __attribute__((aligned(16))) ushort_t As[BM][40];
  __shared__ ushort_t Bs[BK][BN + 2];
  const int t = threadIdx.x;
  const int lane = t & 63, wave = t >> 6;
  const int wm = wave >> 1, wn = wave & 1;
  const int m0 = blockIdx.y * BM, n0 = blockIdx.x * BN;
  const int fB = flags[iB], fbias = flags[ibias];
  f32x4 acc[FM][FN];
#pragma unroll
  for (int i = 0; i < FM; ++i)
#pragma unroll
    for (int j = 0; j < FN; ++j) acc[i][j] = (f32x4)(0.0f);
  const int q = lane >> 4, lm = lane & 15;
  const int arow_s = t >> 2, aslot = t & 3;
  for (int k0 = 0; k0 < K; k0 += BK) {
    __syncthreads();
#pragma unroll
    for (int r = 0; r < BM / 64; ++r) {
      int row = r * 64 + arow_s;
      *(u16x8*)&As[row][aslot * 8] =
          *(const u16x8*)(A + (size_t)(m0 + row) * lda + k0 + aslot * 8);
    }
#pragma unroll
    for (int e = 0; e < (BK * BN) / 256; ++e) {
      int id = e * 256 + t;
      int k = id / BN, n = id % BN;
      Bs[k][n] = f2bf(ldx(B, (size_t)(brow0 + k0 + k) * ldb + bcol0 + n0 + n, fB));
    }
    __syncthreads();
    s16x8 af[FM], bf[FN];
#pragma unroll
    for (int i = 0; i < FM; ++i)
      af[i] = *(const s16x8*)&As[wm * (BM / 2) + i * 16 + lm][q * 8];
#pragma unroll
    for (int j = 0; j < FN; ++j) {
      int nl = wn * (BN / 2) + j * 16 + lm;
      u16x8 tmp;
#pragma unroll
      for (int f = 0; f < 8; ++f) tmp[f] = Bs[q * 8 + f][nl];
      bf[j] = __builtin_bit_cast(s16x8, tmp);
    }
#pragma unroll
    for (int i = 0; i < FM; ++i)
#pragma unroll
      for (int j = 0; j < FN; ++j)
        acc[i][j] = __builtin_amdgcn_mfma_f32_16x16x32_bf16(af[i], bf[j], acc[i][j], 0, 0, 0);
  }
#pragma unroll
  for (int i = 0; i < FM; ++i) {
#pragma unroll
    for (int j = 0; j < FN; ++j) {
      const int col = wn * (BN / 2) + j * 16 + lm;
      float bb = 0.0f;
      if (EPI != 3 || addb) bb = ldx(bias, bias_off + n0 + col, fbias);
#pragma unroll
      for (int r = 0; r < 4; ++r) {
        const int rowg = m0 + wm * (BM / 2) + i * 16 + q * 4 + r;
        float v = acc[i][j][r] + bb;
        if constexpr (EPI == 0) {
          out_bf[(size_t)rowg * ldo + n0 + col] = f2bf(v);
        } else if constexpr (EPI == 1) {
          out_bf[(size_t)rowg * ldo + n0 + col] =
              f2bf(0.5f * v * (1.0f + erff(v * 0.70710678f)));
        } else if constexpr (EPI == 2) {
          const size_t off = (size_t)rowg * D_MODEL + n0 + col;
          yacc[off] = v + ldx(res, off, flags[ires]);
        } else {
          const size_t off = (size_t)rowg * D_MODEL + n0 + col;
          yacc[off] += v;
        }
      }
    }
  }
}

// ------------------------------------------------- attention (r14 coalesced-K)
__device__ __forceinline__ int key_index(int s, int j, int S) {
  int p;
  if (j < 64)       p = s + j - 32;
  else if (j < 102) p = s + (j - 83) * 64;
  else              p = ((j - 102) * (S - 1)) / 25;
  return min(max(p, 0), S - 1);
}

__global__ __launch_bounds__(256, 4)
void attn_kernel(const ushort_t* __restrict__ qkv, ushort_t* __restrict__ out, int S) {
  const int wave = threadIdx.x >> 6, lane = threadIdx.x & 63;
  const int nb = gridDim.x;
  int bid = blockIdx.x;
  if ((nb & 7) == 0) bid = (bid & 7) * (nb >> 3) + (bid >> 3);  // XCD swizzle (bijective)
  const int pair = bid * 4 + wave;          // pair = h*S + s
  const int h = pair / S;
  const int s = pair - h * S;
  const int g = lane >> 3, d8 = (lane & 7) * 8;

  int koff[16];
#pragma unroll
  for (int r = 0; r < 16; ++r)
    koff[r] = key_index(s, r * 8 + g, S) * (3 * D_MODEL);

  u16x8 qv8 = *(const u16x8*)(qkv + (size_t)s * (3 * D_MODEL) + h * HEAD_D + d8);
  float qf[8];
#pragma unroll
  for (int e = 0; e < 8; ++e) qf[e] = bf2f(qv8[e]);

  const ushort_t* kbase = qkv + D_MODEL + h * HEAD_D + d8;
  float pr[16];
  {
    u16x8 kv[8];
#pragma unroll
    for (int r = 0; r < 8; ++r) kv[r] = *(const u16x8*)(kbase + koff[r]);
#pragma unroll
    for (int r = 0; r < 16; ++r) {
      u16x8 cur = kv[r & 7];
      if (r < 8) kv[r & 7] = *(const u16x8*)(kbase + koff[r + 8]);
      float d = 0.f;
#pragma unroll
      for (int e = 0; e < 8; ++e) d += qf[e] * bf2f(cur[e]);
      d += __shfl_xor(d, 1);
      d += __shfl_xor(d, 2);
      d += __shfl_xor(d, 4);
      pr[r] = d * 0.125f;
    }
  }

  float mx = pr[0];
#pragma unroll
  for (int r = 1; r < 16; ++r) mx = fmaxf(mx, pr[r]);
#pragma unroll
  for (int m = 8; m <= 32; m <<= 1) mx = fmaxf(mx, __shfl_xor(mx, m));
  float sm = 0.f;
#pragma unroll
  for (int r = 0; r < 16; ++r) { pr[r] = __expf(pr[r] - mx); sm += pr[r]; }
#pragma unroll
  for (int m = 8; m <= 32; m <<= 1) sm += __shfl_xor(sm, m);
  const float inv = 1.0f / sm;

  const ushort_t* vbase = qkv + 2 * D_MODEL + h * HEAD_D + d8;
  float oacc[8];
#pragma unroll
  for (int e = 0; e < 8; ++e) oacc[e] = 0.f;
  {
    u16x8 vv[8];
#pragma unroll
    for (int r = 0; r < 8; ++r) vv[r] = *(const u16x8*)(vbase + koff[r]);
#pragma unroll
    for (int r = 0; r < 16; ++r) {
      u16x8 cv = vv[r & 7];
      float cp = pr[r] * inv;
      if (r < 8) vv[r & 7] = *(const u16x8*)(vbase + koff[r + 8]);
#pragma unroll
      for (int e = 0; e < 8; ++e) oacc[e] += cp * bf2f(cv[e]);
    }
  }
#pragma unroll
  for (int m = 8; m <= 32; m <<= 1)
#pragma unroll
    for (int e = 0; e < 8; ++e) oacc[e] += __shfl_xor(oacc[e], m);

  if (lane < 8) {
    u16x8 ov;
#pragma unroll
    for (int e = 0; e < 8; ++e) ov[e] = f2bf(oacc[e]);
    *(u16x8*)(out + (size_t)s * D_MODEL + h * HEAD_D + d8) = ov;
  }
}

// ------------------------------------------------- final convert (fallback only)
__global__ __launch_bounds__(256)
void convert_kernel(const float* __restrict__ y, void* __restrict__ out,
                    const int* __restrict__ flags, int n) {
  const int fout = flags[0];
  int i = blockIdx.x * 256 + threadIdx.x;
  if (i < n) {
    float v = y[i];
    if (fout) ((float*)out)[i] = v;
    else      ((ushort_t*)out)[i] = f2bf(v);
  }
}

// ------------------------------------------------- launch
extern "C" void kernel_launch(void* const* d_in, const int* in_sizes, int n_in,
                              void* d_out, int out_size, void* d_ws, size_t ws_size,
                              hipStream_t stream) {
  const int S = in_sizes[0] / D_MODEL;    // 2048
  const size_t sD = (size_t)S * D_MODEL;
  char* ws = (char*)d_ws;

  DetectArgs da;
  for (int i = 0; i < 14; ++i) { da.p[i] = d_in[i]; da.n[i] = in_sizes[i]; }

  ushort_t* h1    = (ushort_t*)d_out;
  ushort_t* attnb = (ushort_t*)d_out;
  ushort_t* h2    = (ushort_t*)d_out;

  const size_t MB = 1024 * 1024;
  if (ws_size >= 12 * MB + 64) {
    const int P  = (ws_size >= 20 * MB) ? 1 : 2;
    const int Nc = D_FFN / P;
    char* wbase = ws + (P == 1 ? 12 : 6) * MB;

    ushort_t* qkv   = (ushort_t*)ws;                       // [0,6M)
    float*    y     = (float*)ws;                          // [0,4M) after qkv dies
    ushort_t* gbuf  = (ushort_t*)(ws + 4 * MB);            // S*Nc bf16 (4 or 8 MB)
    ushort_t* wqkvT = (ushort_t*)wbase;                    // 1.5 MB
    ushort_t* woT   = (ushort_t*)(wbase + 1 * MB + 512 * 1024);  // 0.5 MB
    ushort_t* w1T   = (ushort_t*)(wbase + 2 * MB);         // 2 MB
    ushort_t* w2T   = (ushort_t*)(wbase + 4 * MB);         // 2 MB
    int*      flags = (int*)(wbase + 6 * MB);
    // fused-LN2 buffers (P==1 only: need the extra 25 KB of headroom)
    float*    stats = (float*)(wbase + 6 * MB + 1024);     // 2048 x {sum,sq}
    float*    b1p   = (float*)(wbase + 6 * MB + 1024 + 16384);  // 2048 f32

    detect_all<<<14, 256, 0, stream>>>(da, flags);

    WDesc dq  = { d_in[6],  wqkvT, D_MODEL, 3 * D_MODEL, 6,  0 };
    WDesc dwo = { d_in[8],  woT,   D_MODEL, D_MODEL,     8,  768 };
    WDesc dw1 = { d_in[10], w1T,   D_MODEL, D_FFN,       10, 1024 };
    WDesc dw2 = { d_in[12], w2T,   D_FFN,   D_MODEL,     12, 2048 };

    const int fuse = (P == 1);
    // K2: weight convert (3072) + ln1 (512) + ln2-fold matvec (8, fused only)
    prep_kernel<<<3072 + S / 4 + (fuse ? 8 : 0), 256, 0, stream>>>(
        dq, dwo, dw1, dw2, 3072, S / 4, d_in[0], d_in[2], d_in[3], h1,
        d_in[4], d_in[5], d_in[10], d_in[11],
        fuse ? b1p : nullptr, stats, flags);

    // GEMM1: h1 @ wqkv + bqkv -> qkv  (32x64, 1536 blocks, 6/CU)
    gemm_bt<32, 64, 0, 0><<<dim3(24, S / 32), 256, 0, stream>>>(
        h1, D_MODEL, wqkvT, D_MODEL, D_MODEL, d_in[7], 0,
        nullptr, nullptr, qkv, 3 * D_MODEL, flags, 7, 0, 1,
        nullptr, nullptr, nullptr);

    attn_kernel<<<(S * N_HEADS) / 4, 256, 0, stream>>>(qkv, attnb, S);

    // GEMM2: attnb @ wo + bo + x -> y (+ row stats when fused)
    gemm_bt<32, 32, 2, 0><<<dim3(16, S / 32), 256, 0, stream>>>(
        attnb, D_MODEL, woT, D_MODEL, D_MODEL, d_in[9], 0,
        d_in[0], y, nullptr, D_MODEL, flags, 9, 0, 1,
        nullptr, nullptr, fuse ? stats : nullptr);

    if (P == 1) {
      // GEMM3 (LN2 fused): normalize y in staging; w1T pre-scaled by g;
      // bias = b1 + ln2_b . w1 (f32 -> flags[14]=1)
      gemm_bt<32, 64, 1, 1><<<dim3(D_FFN / 64, S / 32), 256, 0, stream>>>(
          nullptr, D_MODEL, w1T, D_MODEL, D_MODEL,
          b1p, 0, nullptr, nullptr, gbuf, D_FFN, flags, 14, 0, 1,
          y, stats, nullptr);
      // GEMM4: out = y + gbuf @ w2 + b2  (K=2048; 32x32, 1024 blocks, 4/CU)
      gemm_bt<32, 32, 4, 0><<<dim3(16, S / 32), 256, 0, stream>>>(
          gbuf, D_FFN, w2T, D_FFN, D_FFN, d_in[13], 0,
          nullptr, y, (ushort_t*)d_out, D_MODEL, flags, 13, 0, 1,
          nullptr, nullptr, nullptr);
    } else {
      ln2_kernel<<<S / 4, 256, 0, stream>>>(y, d_in[4], d_in[5], h2, flags);
      gemm_bt<32, 64, 1, 0><<<dim3(Nc / 64, S / 32), 256, 0, stream>>>(
          h2, D_MODEL, w1T, D_MODEL, D_MODEL,
          d_in[11], 0, nullptr, nullptr, gbuf, Nc, flags, 11, 0, 1,
          nullptr, nullptr, nullptr);
      gemm_bt<32, 32, 3, 0><<<dim3(16, S / 32), 256, 0, stream>>>(
          gbuf, Nc, w2T, D_FFN, Nc, d_in[13], 0,
          nullptr, y, nullptr, D_MODEL, flags, 13, 0, 1,
          nullptr, nullptr, nullptr);
      gemm_bt<32, 64, 1, 0><<<dim3(Nc / 64, S / 32), 256, 0, stream>>>(
          h2, D_MODEL, w1T + (size_t)Nc * D_MODEL, D_MODEL, D_MODEL,
          d_in[11], Nc, nullptr, nullptr, gbuf, Nc, flags, 11, 0, 1,
          nullptr, nullptr, nullptr);
      gemm_bt<32, 32, 4, 0><<<dim3(16, S / 32), 256, 0, stream>>>(
          gbuf, Nc, w2T + (size_t)Nc, D_FFN, Nc, d_in[13], 0,
          nullptr, y, (ushort_t*)d_out, D_MODEL, flags, 13, 0, 0,
          nullptr, nullptr, nullptr);
    }
  } else {
    // fallback: round-6 proven path
    int P;
    if      (ws_size >= 12ull * MB + 4096) P = 1;
    else if (ws_size >=  8ull * MB + 4096) P = 2;
    else                                   P = 4;
    const int Nc = D_FFN / P;
    const size_t gbuf_bytes = (size_t)S * Nc * 2;
    const size_t qkv_bytes  = 3 * sD * 2;
    const size_t fo = 4ull * sD + gbuf_bytes;
    const size_t flags_pos = (qkv_bytes > fo ? qkv_bytes : fo);

    ushort_t* qkv  = (ushort_t*)ws;
    float*    y    = (float*)ws;
    ushort_t* gbuf = (ushort_t*)(ws + 4 * sD);
    int*      flags = (int*)(ws + flags_pos);

    detect_all<<<14, 256, 0, stream>>>(da, flags);
    ln1_kernel<<<S / 4, 256, 0, stream>>>(d_in[0], d_in[2], d_in[3], h1, flags);
    gemm_nn<128, 128, 0><<<dim3((3 * D_MODEL) / 128, S / 128), 256, 0, stream>>>(
        h1, D_MODEL, D_MODEL, d_in[6], 3 * D_MODEL, 0, 0, d_in[7], 0,
        nullptr, nullptr, qkv, 3 * D_MODEL, flags, 6, 7, 0, 1);
    attn_kernel<<<(S * N_HEADS) / 4, 256, 0, stream>>>(qkv, attnb, S);
    gemm_nn<64, 64, 2><<<dim3(D_MODEL / 64, S / 64), 256, 0, stream>>>(
        attnb, D_MODEL, D_MODEL, d_in[8], D_MODEL, 0, 0, d_in[9], 0,
        d_in[0], y, nullptr, D_MODEL, flags, 8, 9, 0, 1);
    ln2_kernel<<<S / 4, 256, 0, stream>>>(y, d_in[4], d_in[5], h2, flags);
    for (int p = 0; p < P; ++p) {
      if (Nc >= 1024) {
        gemm_nn<128, 128, 1><<<dim3(Nc / 128, S / 128), 256, 0, stream>>>(
            h2, D_MODEL, D_MODEL, d_in[10], D_FFN, 0, p * Nc, d_in[11], p * Nc,
            nullptr, nullptr, gbuf, Nc, flags, 10, 11, 0, 1);
      } else {
        gemm_nn<64, 64, 1><<<dim3(Nc / 64, S / 64), 256, 0, stream>>>(
            h2, D_MODEL, D_MODEL, d_in[10], D_FFN, 0, p * Nc, d_in[11], p * Nc,
            nullptr, nullptr, gbuf, Nc, flags, 10, 11, 0, 1);
      }
      gemm_nn<64, 64, 3><<<dim3(D_MODEL / 64, S / 64), 256, 0, stream>>>(
          gbuf, Nc, Nc, d_in[12], D_MODEL, p * Nc, 0, d_in[13], 0,
          nullptr, y, nullptr, D_MODEL, flags, 12, 13, 0, p == 0 ? 1 : 0);
    }
    convert_kernel<<<(int)((sD + 255) / 256), 256, 0, stream>>>(y, d_out, flags, (int)sD);
  }
}

// Round 7
// 187.701 us; speedup vs baseline: 1.8574x; 1.8574x over previous
//
#include <hip/hip_runtime.h>
#include <math.h>

typedef float f32x4 __attribute__((ext_vector_type(4)));
typedef short s16x8 __attribute__((ext_vector_type(8)));
typedef unsigned short u16x8 __attribute__((ext_vector_type(8)));
typedef unsigned short ushort_t;
typedef unsigned int uint_t;

#define D_MODEL 512
#define N_HEADS 8
#define HEAD_D  64
#define D_FFN   2048

__device__ __forceinline__ float bf2f(unsigned short u) {
  union { unsigned int i; float f; } c; c.i = ((unsigned int)u) << 16; return c.f;
}
__device__ __forceinline__ unsigned short f2bf(float f) {
  union { float f; unsigned int i; } c; c.f = f;
  unsigned int x = c.i;
  return (unsigned short)((x + 0x7FFFu + ((x >> 16) & 1u)) >> 16);
}
__device__ __forceinline__ float ldx(const void* p, size_t i, int f) {
  return f ? ((const float*)p)[i] : bf2f(((const ushort_t*)p)[i]);
}

// ------------------------------------------------- fused dtype detector
// One tiny upfront kernel; every consumer pays a single scalar flags[] load.
// (R1/R2 lesson: per-block inline probes cost ~13 µs of tail latency.)
// R7: blocks >=14 zero the stats/b1p buffers for the LN2-fold path (must
// strictly precede prep's atomicAdds — stream order guarantees it).
struct DetectArgs { const void* p[14]; int n[14]; };

__global__ __launch_bounds__(256)
void detect_all(DetectArgs a, int* __restrict__ flags,
                float* __restrict__ stats, float* __restrict__ b1p, int S) {
  __shared__ int cnt[2];
  const int b = blockIdx.x;
  const int t = threadIdx.x;
  if (b >= 14) {
    const int i = (b - 14) * 256 + t;
    if (i < S) { stats[2 * i] = 0.f; stats[2 * i + 1] = 0.f; }
    if (i < D_FFN) b1p[i] = 0.f;
    return;
  }
  if (b == 0 && t == 64) flags[14] = 1;   // constant "f32" flag for fused b1'
  if (b == 1) { if (t == 0) flags[1] = 0; return; }
  if (t == 0) { cnt[0] = 0; cnt[1] = 0; }
  __syncthreads();
  const int n_u32 = a.n[b] >> 1;
  const int sample = n_u32 < 256 ? n_u32 : 256;
  if (t < sample) {
    uint_t u = ((const uint_t*)a.p[b])[t];
    if (u != 0u) {
      atomicAdd(&cnt[0], 1);
      int e = (u >> 7) & 0xFF;
      if (e >= 0x70 && e <= 0x83) atomicAdd(&cnt[1], 1);
    }
  }
  __syncthreads();
  if (t == 0) flags[b] = (cnt[0] >= 32 && cnt[1] * 4 <= cnt[0]) ? 1 : 0;
}

// ------------------------------------------------- prep: wconv + ln1 + ln2-fold
// LN2 fold: (x_hat*g + b) @ w1 == x_hat @ (g(*)w1) + (b.w1 + b1).
//  - w1 conversion scales row k by ln2_g[k] (when fusing).
//  - R7 matvec fix (was 183 µs/dispatch!): 128 blocks (16 k-slices x 8
//    n-slices) instead of 8; per-thread chain 512 -> 32 loads; dtype branch
//    HOISTED out of the loop (branchy ldx per iter serialized the memory
//    pipe to ~1 HBM latency per element); b2 slice staged in LDS;
//    partials combined by atomicAdd (16 adds/element).
struct WDesc { const void* src; ushort_t* dst; int Kd, Nd, flag, tile0; };

__global__ __launch_bounds__(256)
void prep_kernel(WDesc w0, WDesc w1, WDesc w2, WDesc w3, int nconv, int nln,
                 const void* __restrict__ x, const void* __restrict__ g,
                 const void* __restrict__ b, ushort_t* __restrict__ h1,
                 const void* __restrict__ g2, const void* __restrict__ b2,
                 const void* __restrict__ w1src, const void* __restrict__ b1src,
                 float* __restrict__ b1p,
                 const int* __restrict__ flags) {
  __shared__ ushort_t tile[32][33];
  __shared__ float sb2[32];
  const int blk = blockIdx.x;
  const int t = threadIdx.x;
  if (blk >= nconv + nln) {
    // ----- ln2-fold matvec (fused only): b1p[n] += b2 . w1[:,n] (+ b1[n])
    const int mb = blk - nconv - nln;    // 0..127
    const int ks = mb >> 3;              // 16 k-slices of 32
    const int n  = (mb & 7) * 256 + t;   // 8 n-slices of 256
    if (t < 32) sb2[t] = ldx(b2, ks * 32 + t, flags[5]);
    __syncthreads();
    const int fw1 = flags[10];
    float acc = 0.f;
    if (fw1) {
      const float* w = (const float*)w1src + (size_t)(ks * 32) * D_FFN + n;
#pragma unroll
      for (int k = 0; k < 32; ++k) acc += sb2[k] * w[(size_t)k * D_FFN];
    } else {
      const ushort_t* w = (const ushort_t*)w1src + (size_t)(ks * 32) * D_FFN + n;
#pragma unroll
      for (int k = 0; k < 32; ++k) acc += sb2[k] * bf2f(w[(size_t)k * D_FFN]);
    }
    if (ks == 0) acc += ldx(b1src, n, flags[11]);
    atomicAdd(&b1p[n], acc);
    return;
  }
  if (blk >= nconv) {
    // ----- ln1 path (4 rows per block)
    const int fx = flags[0], fg = flags[2], fb = flags[3];
    const int row = (blk - nconv) * 4 + (t >> 6);
    const int lane = t & 63;
    float v[8], sum = 0.f, sq = 0.f;
#pragma unroll
    for (int i = 0; i < 8; ++i) {
      v[i] = ldx(x, (size_t)row * D_MODEL + lane * 8 + i, fx);
      sum += v[i]; sq += v[i] * v[i];
    }
#pragma unroll
    for (int o = 32; o > 0; o >>= 1) { sum += __shfl_xor(sum, o); sq += __shfl_xor(sq, o); }
    const float mu = sum * (1.0f / D_MODEL);
    const float var = sq * (1.0f / D_MODEL) - mu * mu;
    const float rstd = rsqrtf(var + 1e-5f);
#pragma unroll
    for (int i = 0; i < 8; ++i) {
      int c = lane * 8 + i;
      h1[(size_t)row * D_MODEL + c] =
          f2bf((v[i] - mu) * rstd * ldx(g, c, fg) + ldx(b, c, fb));
    }
    return;
  }
  // ----- weight convert+transpose path
  WDesc d = (blk < w1.tile0) ? w0 : (blk < w2.tile0) ? w1 : (blk < w3.tile0) ? w2 : w3;
  const int lt = blk - d.tile0;
  const int tn = d.Nd / 32;
  const int bk = lt / tn, bn = lt % tn;
  const int f = flags[d.flag];
  const int scale_w1 = (d.flag == 10 && b1p != nullptr);
  const int fg2 = flags[4];
  const int tx = t & 31, ty = t >> 5;
#pragma unroll
  for (int r = 0; r < 4; ++r) {
    int k = bk * 32 + ty * 4 + r;
    float val = ldx(d.src, (size_t)k * d.Nd + bn * 32 + tx, f);
    if (scale_w1) val *= ldx(g2, k, fg2);
    tile[ty * 4 + r][tx] = f2bf(val);
  }
  __syncthreads();
#pragma unroll
  for (int r = 0; r < 4; ++r) {
    int n = bn * 32 + ty * 4 + r;
    d.dst[(size_t)n * d.Kd + bk * 32 + tx] = tile[tx][ty * 4 + r];
  }
}

// ------------------------------------------------- LN kernels
__global__ __launch_bounds__(256)
void ln1_kernel(const void* __restrict__ x, const void* __restrict__ g,
                const void* __restrict__ b, ushort_t* __restrict__ out,
                const int* __restrict__ flags) {
  const int fx = flags[0], fg = flags[2], fb = flags[3];
  const int row = blockIdx.x * 4 + (threadIdx.x >> 6);
  const int lane = threadIdx.x & 63;
  float v[8], sum = 0.f, sq = 0.f;
#pragma unroll
  for (int i = 0; i < 8; ++i) {
    v[i] = ldx(x, (size_t)row * D_MODEL + lane * 8 + i, fx);
    sum += v[i]; sq += v[i] * v[i];
  }
#pragma unroll
  for (int o = 32; o > 0; o >>= 1) { sum += __shfl_xor(sum, o); sq += __shfl_xor(sq, o); }
  const float mu = sum * (1.0f / D_MODEL);
  const float var = sq * (1.0f / D_MODEL) - mu * mu;
  const float rstd = rsqrtf(var + 1e-5f);
#pragma unroll
  for (int i = 0; i < 8; ++i) {
    int c = lane * 8 + i;
    out[(size_t)row * D_MODEL + c] =
        f2bf((v[i] - mu) * rstd * ldx(g, c, fg) + ldx(b, c, fb));
  }
}

__global__ __launch_bounds__(256)
void ln2_kernel(const float* __restrict__ y, const void* __restrict__ g,
                const void* __restrict__ b, ushort_t* __restrict__ out,
                const int* __restrict__ flags) {
  const int fg = flags[4], fb = flags[5];
  const int row = blockIdx.x * 4 + (threadIdx.x >> 6);
  const int lane = threadIdx.x & 63;
  float v[8], sum = 0.f, sq = 0.f;
#pragma unroll
  for (int i = 0; i < 8; ++i) {
    v[i] = y[(size_t)row * D_MODEL + lane * 8 + i];
    sum += v[i]; sq += v[i] * v[i];
  }
#pragma unroll
  for (int o = 32; o > 0; o >>= 1) { sum += __shfl_xor(sum, o); sq += __shfl_xor(sq, o); }
  const float mu = sum * (1.0f / D_MODEL);
  const float var = sq * (1.0f / D_MODEL) - mu * mu;
  const float rstd = rsqrtf(var + 1e-5f);
#pragma unroll
  for (int i = 0; i < 8; ++i) {
    int c = lane * 8 + i;
    out[(size_t)row * D_MODEL + c] =
        f2bf((v[i] - mu) * rstd * ldx(g, c, fg) + ldx(b, c, fb));
  }
}

// ------------------------------------------------- pipelined MFMA GEMM, BK=64
// R5 write-early dbuf (proven): loads issued one full K-step ahead of their
// swrite; swizzled granules ((k>>3)^(row&7)); ONE barrier per K-step; 24 KB
// LDS -> 6 blocks/CU for 32x64.
//  - LNA: A operand is f32 y, normalized on-the-fly in staging using per-row
//    {sum,sq} stats (computed by gemm2's epilogue). (ln2 fold; BM==32.)
//  - EPI==2 + stats_out: epilogue 16-lane-reduces each output row slice and
//    atomically accumulates {sum, sum^2} for the LNA consumer.
// EPI: 0 = +bias -> bf16            1 = gelu(+bias) -> bf16
//      2 = y[off] = v+bias+res      3 = y[off] += v (+bias if addb)
//      4 = out[off] = y[off] + v (+bias if addb; dtype per flags[ires])
template <int BM, int BN, int EPI, int LNA>
__global__ __launch_bounds__(256)
void gemm_bt(const ushort_t* __restrict__ A, int lda,
             const ushort_t* __restrict__ BT, int ldb, int K,
             const void* __restrict__ bias, int bias_off,
             const void* __restrict__ res,
             float* __restrict__ yacc,
             ushort_t* __restrict__ out_bf, int ldo,
             const int* __restrict__ flags, int ibias, int ires, int addb,
             const float* __restrict__ af32, const float* __restrict__ stats,
             float* __restrict__ stats_out) {
  constexpr int BK = 64;
  constexpr int FM = BM / 32, FN = BN / 32;
  constexpr int AG = BM / 32, BG = BN / 32;   // staging groups of 32 rows
  static_assert(!LNA || BM == 32, "LNA staging assumes AG==1");
  __shared__ __attribute__((aligned(16))) ushort_t As[2][BM][64];
  __shared__ __attribute__((aligned(16))) ushort_t Bs[2][BN][64];

  const int t = threadIdx.x;
  const int lane = t & 63, wave = t >> 6;
  const int wm = wave >> 1, wn = wave & 1;
  const int q = lane >> 4, lm = lane & 15;
  const int m0 = blockIdx.y * BM, n0 = blockIdx.x * BN;
  const int srow = t >> 3, sslot = t & 7;   // 32 rows x 8 granules per pass
  const int wslot = (sslot ^ (srow & 7)) * 8;  // swizzled write column
  const int xorg = lm & 7;                   // fragment-read swizzle

  f32x4 acc[FM][FN];
#pragma unroll
  for (int i = 0; i < FM; ++i)
#pragma unroll
    for (int j = 0; j < FN; ++j) acc[i][j] = (f32x4)(0.0f);

  u16x8 av[AG], bv[BG];
  f32x4 avf0, avf1; float2 sst;

  auto gload = [&](int k0) {
    if constexpr (LNA) {
      const float* yr = af32 + (size_t)(m0 + srow) * lda + k0 + sslot * 8;
      avf0 = *(const f32x4*)yr;
      avf1 = *(const f32x4*)(yr + 4);
      sst = *(const float2*)&stats[(m0 + srow) * 2];
    } else {
#pragma unroll
      for (int r = 0; r < AG; ++r)
        av[r] = *(const u16x8*)(A + (size_t)(m0 + r * 32 + srow) * lda + k0 + sslot * 8);
    }
#pragma unroll
    for (int r = 0; r < BG; ++r)
      bv[r] = *(const u16x8*)(BT + (size_t)(n0 + r * 32 + srow) * ldb + k0 + sslot * 8);
  };
  auto swrite = [&](int buf) {
    if constexpr (LNA) {
      const float mu = sst.x * (1.0f / D_MODEL);
      const float rstd = rsqrtf(sst.y * (1.0f / D_MODEL) - mu * mu + 1e-5f);
      u16x8 w;
#pragma unroll
      for (int e = 0; e < 4; ++e) {
        w[e]     = f2bf((avf0[e] - mu) * rstd);
        w[e + 4] = f2bf((avf1[e] - mu) * rstd);
      }
      *(u16x8*)&As[buf][srow][wslot] = w;
    } else {
#pragma unroll
      for (int r = 0; r < AG; ++r) *(u16x8*)&As[buf][r * 32 + srow][wslot] = av[r];
    }
#pragma unroll
    for (int r = 0; r < BG; ++r) *(u16x8*)&Bs[buf][r * 32 + srow][wslot] = bv[r];
  };
  auto frag_mfma = [&](int buf, int kh) {
    s16x8 af[FM], bf[FN];
    const int rcol = ((kh * 4 + q) ^ xorg) * 8;   // swizzled read column
#pragma unroll
    for (int i = 0; i < FM; ++i)
      af[i] = *(const s16x8*)&As[buf][wm * (BM / 2) + i * 16 + lm][rcol];
#pragma unroll
    for (int j = 0; j < FN; ++j)
      bf[j] = *(const s16x8*)&Bs[buf][wn * (BN / 2) + j * 16 + lm][rcol];
#pragma unroll
    for (int i = 0; i < FM; ++i)
#pragma unroll
      for (int j = 0; j < FN; ++j)
        acc[i][j] = __builtin_amdgcn_mfma_f32_16x16x32_bf16(af[i], bf[j], acc[i][j], 0, 0, 0);
  };

  const int NT = K / BK;
  gload(0);
  swrite(0);            // exposed vmcnt once (prologue only)
  __syncthreads();
  gload(BK);            // tile 1 in flight across the whole first K-step
  int buf = 0;
  for (int kt = 1; kt < NT; ++kt) {
    swrite(buf ^ 1);    // stage tile kt (issued last iteration: latency covered)
    if (kt + 1 < NT) gload((kt + 1) * BK);   // issue tile kt+1
    frag_mfma(buf, 0);  // compute tile kt-1
    frag_mfma(buf, 1);
    __syncthreads();    // ONE barrier per K-step
    buf ^= 1;
  }
  frag_mfma(buf, 0);    // compute tile NT-1
  frag_mfma(buf, 1);

  const int fbias = flags[ibias];
  float yv[4] = {0.f, 0.f, 0.f, 0.f};
#pragma unroll
  for (int i = 0; i < FM; ++i) {
#pragma unroll
    for (int j = 0; j < FN; ++j) {
      const int colg = n0 + wn * (BN / 2) + j * 16 + lm;
      float bb = 0.0f;
      if (EPI <= 2 || addb) bb = ldx(bias, bias_off + colg, fbias);
#pragma unroll
      for (int r = 0; r < 4; ++r) {
        const int rowg = m0 + wm * (BM / 2) + i * 16 + q * 4 + r;
        float v = acc[i][j][r] + bb;
        const size_t off = (size_t)rowg * ldo + colg;
        if constexpr (EPI == 0) {
          out_bf[off] = f2bf(v);
        } else if constexpr (EPI == 1) {
          out_bf[off] = f2bf(0.5f * v * (1.0f + erff(v * 0.70710678f)));
        } else if constexpr (EPI == 2) {
          float fin = v + ldx(res, off, flags[ires]);
          yacc[off] = fin;
          yv[r] = fin;
        } else if constexpr (EPI == 3) {
          yacc[off] += v;
        } else {
          float fin = yacc[off] + v;
          if (flags[ires]) ((float*)(void*)out_bf)[off] = fin;
          else             out_bf[off] = f2bf(fin);
        }
      }
    }
  }
  if constexpr (EPI == 2) {
    static_assert(EPI != 2 || (FM == 1 && FN == 1), "stats path assumes 32x32");
    if (stats_out) {
#pragma unroll
      for (int r = 0; r < 4; ++r) {
        float s1 = yv[r], s2 = yv[r] * yv[r];
#pragma unroll
        for (int m = 1; m <= 8; m <<= 1) { s1 += __shfl_xor(s1, m); s2 += __shfl_xor(s2, m); }
        if (lm == 0) {
          const int row = m0 + wm * 16 + q * 4 + r;
          atomicAdd(&stats_out[row * 2], s1);
          atomicAdd(&stats_out[row * 2 + 1], s2);
        }
      }
    }
  }
}

// ------------------------------------------------- legacy GEMM (fallback path, r6-proven)
template <int BM, int BN, int EPI>
__global__ __launch_bounds__(256)
void gemm_nn(const ushort_t* __restrict__ A, int lda, int K,
             const void* __restrict__ B, int ldb, int brow0, int bcol0,
             const void* __restrict__ bias, int bias_off,
             const void* __restrict__ res,
             float* __restrict__ yacc,
             ushort_t* __restrict__ out_bf, int ldo,
             const int* __restrict__ flags, int iB, int ibias, int ires, int addb) {
  constexpr int BK = 32;
  constexpr int FM = BM / 32, FN = BN / 32;
  __shared__ __attribute__((aligned(16))) ushort_t As[BM][40];
  __shared__ ushort_t Bs[BK][BN + 2];
  const int t = threadIdx.x;
  const int lane = t & 63, wave = t >> 6;
  const int wm = wave >> 1, wn = wave & 1;
  const int m0 = blockIdx.y * BM, n0 = blockIdx.x * BN;
  const int fB = flags[iB], fbias = flags[ibias];
  f32x4 acc[FM][FN];
#pragma unroll
  for (int i = 0; i < FM; ++i)
#pragma unroll
    for (int j = 0; j < FN; ++j) acc[i][j] = (f32x4)(0.0f);
  const int q = lane >> 4, lm = lane & 15;
  const int arow_s = t >> 2, aslot = t & 3;
  for (int k0 = 0; k0 < K; k0 += BK) {
    __syncthreads();
#pragma unroll
    for (int r = 0; r < BM / 64; ++r) {
      int row = r * 64 + arow_s;
      *(u16x8*)&As[row][aslot * 8] =
          *(const u16x8*)(A + (size_t)(m0 + row) * lda + k0 + aslot * 8);
    }
#pragma unroll
    for (int e = 0; e < (BK * BN) / 256; ++e) {
      int id = e * 256 + t;
      int k = id / BN, n = id % BN;
      Bs[k][n] = f2bf(ldx(B, (size_t)(brow0 + k0 + k) * ldb + bcol0 + n0 + n, fB));
    }
    __syncthreads();
    s16x8 af[FM], bf[FN];
#pragma unroll
    for (int i = 0; i < FM; ++i)
      af[i] = *(const s16x8*)&As[wm * (BM / 2) + i * 16 + lm][q * 8];
#pragma unroll
    for (int j = 0; j < FN; ++j) {
      int nl = wn * (BN / 2) + j * 16 + lm;
      u16x8 tmp;
#pragma unroll
      for (int f = 0; f < 8; ++f) tmp[f] = Bs[q * 8 + f][nl];
      bf[j] = __builtin_bit_cast(s16x8, tmp);
    }
#pragma unroll
    for (int i = 0; i < FM; ++i)
#pragma unroll
      for (int j = 0; j < FN; ++j)
        acc[i][j] = __builtin_amdgcn_mfma_f32_16x16x32_bf16(af[i], bf[j], acc[i][j], 0, 0, 0);
  }
#pragma unroll
  for (int i = 0; i < FM; ++i) {
#pragma unroll
    for (int j = 0; j < FN; ++j) {
      const int col = wn * (BN / 2) + j * 16 + lm;
      float bb = 0.0f;
      if (EPI != 3 || addb) bb = ldx(bias, bias_off + n0 + col, fbias);
#pragma unroll
      for (int r = 0; r < 4; ++r) {
        const int rowg = m0 + wm * (BM / 2) + i * 16 + q * 4 + r;
        float v = acc[i][j][r] + bb;
        if constexpr (EPI == 0) {
          out_bf[(size_t)rowg * ldo + n0 + col] = f2bf(v);
        } else if constexpr (EPI == 1) {
          out_bf[(size_t)rowg * ldo + n0 + col] =
              f2bf(0.5f * v * (1.0f + erff(v * 0.70710678f)));
        } else if constexpr (EPI == 2) {
          const size_t off = (size_t)rowg * D_MODEL + n0 + col;
          yacc[off] = v + ldx(res, off, flags[ires]);
        } else {
          const size_t off = (size_t)rowg * D_MODEL + n0 + col;
          yacc[off] += v;
        }
      }
    }
  }
}

// ------------------------------------------------- attention (r14 coalesced-K)
__device__ __forceinline__ int key_index(int s, int j, int S) {
  int p;
  if (j < 64)       p = s + j - 32;
  else if (j < 102) p = s + (j - 83) * 64;
  else              p = ((j - 102) * (S - 1)) / 25;
  return min(max(p, 0), S - 1);
}

__global__ __launch_bounds__(256, 4)
void attn_kernel(const ushort_t* __restrict__ qkv, ushort_t* __restrict__ out, int S) {
  const int wave = threadIdx.x >> 6, lane = threadIdx.x & 63;
  const int nb = gridDim.x;
  int bid = blockIdx.x;
  if ((nb & 7) == 0) bid = (bid & 7) * (nb >> 3) + (bid >> 3);  // XCD swizzle (bijective)
  const int pair = bid * 4 + wave;          // pair = h*S + s
  const int h = pair / S;
  const int s = pair - h * S;
  const int g = lane >> 3, d8 = (lane & 7) * 8;

  int koff[16];
#pragma unroll
  for (int r = 0; r < 16; ++r)
    koff[r] = key_index(s, r * 8 + g, S) * (3 * D_MODEL);

  u16x8 qv8 = *(const u16x8*)(qkv + (size_t)s * (3 * D_MODEL) + h * HEAD_D + d8);
  float qf[8];
#pragma unroll
  for (int e = 0; e < 8; ++e) qf[e] = bf2f(qv8[e]);

  const ushort_t* kbase = qkv + D_MODEL + h * HEAD_D + d8;
  float pr[16];
  {
    u16x8 kv[8];
#pragma unroll
    for (int r = 0; r < 8; ++r) kv[r] = *(const u16x8*)(kbase + koff[r]);
#pragma unroll
    for (int r = 0; r < 16; ++r) {
      u16x8 cur = kv[r & 7];
      if (r < 8) kv[r & 7] = *(const u16x8*)(kbase + koff[r + 8]);
      float d = 0.f;
#pragma unroll
      for (int e = 0; e < 8; ++e) d += qf[e] * bf2f(cur[e]);
      d += __shfl_xor(d, 1);
      d += __shfl_xor(d, 2);
      d += __shfl_xor(d, 4);
      pr[r] = d * 0.125f;
    }
  }

  float mx = pr[0];
#pragma unroll
  for (int r = 1; r < 16; ++r) mx = fmaxf(mx, pr[r]);
#pragma unroll
  for (int m = 8; m <= 32; m <<= 1) mx = fmaxf(mx, __shfl_xor(mx, m));
  float sm = 0.f;
#pragma unroll
  for (int r = 0; r < 16; ++r) { pr[r] = __expf(pr[r] - mx); sm += pr[r]; }
#pragma unroll
  for (int m = 8; m <= 32; m <<= 1) sm += __shfl_xor(sm, m);
  const float inv = 1.0f / sm;

  const ushort_t* vbase = qkv + 2 * D_MODEL + h * HEAD_D + d8;
  float oacc[8];
#pragma unroll
  for (int e = 0; e < 8; ++e) oacc[e] = 0.f;
  {
    u16x8 vv[8];
#pragma unroll
    for (int r = 0; r < 8; ++r) vv[r] = *(const u16x8*)(vbase + koff[r]);
#pragma unroll
    for (int r = 0; r < 16; ++r) {
      u16x8 cv = vv[r & 7];
      float cp = pr[r] * inv;
      if (r < 8) vv[r & 7] = *(const u16x8*)(vbase + koff[r + 8]);
#pragma unroll
      for (int e = 0; e < 8; ++e) oacc[e] += cp * bf2f(cv[e]);
    }
  }
#pragma unroll
  for (int m = 8; m <= 32; m <<= 1)
#pragma unroll
    for (int e = 0; e < 8; ++e) oacc[e] += __shfl_xor(oacc[e], m);

  if (lane < 8) {
    u16x8 ov;
#pragma unroll
    for (int e = 0; e < 8; ++e) ov[e] = f2bf(oacc[e]);
    *(u16x8*)(out + (size_t)s * D_MODEL + h * HEAD_D + d8) = ov;
  }
}

// ------------------------------------------------- final convert (fallback only)
__global__ __launch_bounds__(256)
void convert_kernel(const float* __restrict__ y, void* __restrict__ out,
                    const int* __restrict__ flags, int n) {
  const int fout = flags[0];
  int i = blockIdx.x * 256 + threadIdx.x;
  if (i < n) {
    float v = y[i];
    if (fout) ((float*)out)[i] = v;
    else      ((ushort_t*)out)[i] = f2bf(v);
  }
}

// ------------------------------------------------- launch
extern "C" void kernel_launch(void* const* d_in, const int* in_sizes, int n_in,
                              void* d_out, int out_size, void* d_ws, size_t ws_size,
                              hipStream_t stream) {
  const int S = in_sizes[0] / D_MODEL;    // 2048
  const size_t sD = (size_t)S * D_MODEL;
  char* ws = (char*)d_ws;

  DetectArgs da;
  for (int i = 0; i < 14; ++i) { da.p[i] = d_in[i]; da.n[i] = in_sizes[i]; }

  ushort_t* h1    = (ushort_t*)d_out;
  ushort_t* attnb = (ushort_t*)d_out;
  ushort_t* h2    = (ushort_t*)d_out;

  const size_t MB = 1024 * 1024;
  if (ws_size >= 12 * MB + 64) {
    const int P  = (ws_size >= 20 * MB) ? 1 : 2;
    const int Nc = D_FFN / P;
    char* wbase = ws + (P == 1 ? 12 : 6) * MB;

    ushort_t* qkv   = (ushort_t*)ws;                       // [0,6M)
    float*    y     = (float*)ws;                          // [0,4M) after qkv dies
    ushort_t* gbuf  = (ushort_t*)(ws + 4 * MB);            // S*Nc bf16 (4 or 8 MB)
    ushort_t* wqkvT = (ushort_t*)wbase;                    // 1.5 MB
    ushort_t* woT   = (ushort_t*)(wbase + 1 * MB + 512 * 1024);  // 0.5 MB
    ushort_t* w1T   = (ushort_t*)(wbase + 2 * MB);         // 2 MB
    ushort_t* w2T   = (ushort_t*)(wbase + 4 * MB);         // 2 MB
    int*      flags = (int*)(wbase + 6 * MB);
    // fused-LN2 buffers (P==1 only: need the extra headroom)
    float*    stats = (float*)(wbase + 6 * MB + 1024);     // S x {sum,sq}
    float*    b1p   = (float*)(wbase + 6 * MB + 1024 + 16384);  // D_FFN f32

    const int fuse = (P == 1);
    const int nzero = fuse ? (S > D_FFN ? S : D_FFN) / 256 : 0;
    detect_all<<<14 + nzero, 256, 0, stream>>>(da, flags, stats, b1p, S);

    WDesc dq  = { d_in[6],  wqkvT, D_MODEL, 3 * D_MODEL, 6,  0 };
    WDesc dwo = { d_in[8],  woT,   D_MODEL, D_MODEL,     8,  768 };
    WDesc dw1 = { d_in[10], w1T,   D_MODEL, D_FFN,       10, 1024 };
    WDesc dw2 = { d_in[12], w2T,   D_FFN,   D_MODEL,     12, 2048 };

    // K2: weight convert (3072) + ln1 (512) + ln2-fold matvec (128, fused)
    prep_kernel<<<3072 + S / 4 + (fuse ? 128 : 0), 256, 0, stream>>>(
        dq, dwo, dw1, dw2, 3072, S / 4, d_in[0], d_in[2], d_in[3], h1,
        d_in[4], d_in[5], d_in[10], d_in[11],
        fuse ? b1p : nullptr, flags);

    // GEMM1: h1 @ wqkv + bqkv -> qkv  (32x64, 1536 blocks, 6/CU)
    gemm_bt<32, 64, 0, 0><<<dim3(24, S / 32), 256, 0, stream>>>(
        h1, D_MODEL, wqkvT, D_MODEL, D_MODEL, d_in[7], 0,
        nullptr, nullptr, qkv, 3 * D_MODEL, flags, 7, 0, 1,
        nullptr, nullptr, nullptr);

    attn_kernel<<<(S * N_HEADS) / 4, 256, 0, stream>>>(qkv, attnb, S);

    // GEMM2: attnb @ wo + bo + x -> y (+ row stats when fused)
    gemm_bt<32, 32, 2, 0><<<dim3(16, S / 32), 256, 0, stream>>>(
        attnb, D_MODEL, woT, D_MODEL, D_MODEL, d_in[9], 0,
        d_in[0], y, nullptr, D_MODEL, flags, 9, 0, 1,
        nullptr, nullptr, fuse ? stats : nullptr);

    if (P == 1) {
      // GEMM3 (LN2 fused): normalize y in staging; w1T pre-scaled by g;
      // bias = b1 + ln2_b . w1 (f32 -> flags[14]=1)
      gemm_bt<32, 64, 1, 1><<<dim3(D_FFN / 64, S / 32), 256, 0, stream>>>(
          nullptr, D_MODEL, w1T, D_MODEL, D_MODEL,
          b1p, 0, nullptr, nullptr, gbuf, D_FFN, flags, 14, 0, 1,
          y, stats, nullptr);
      // GEMM4: out = y + gbuf @ w2 + b2  (K=2048; 32x32, 1024 blocks, 4/CU)
      gemm_bt<32, 32, 4, 0><<<dim3(16, S / 32), 256, 0, stream>>>(
          gbuf, D_FFN, w2T, D_FFN, D_FFN, d_in[13], 0,
          nullptr, y, (ushort_t*)d_out, D_MODEL, flags, 13, 0, 1,
          nullptr, nullptr, nullptr);
    } else {
      ln2_kernel<<<S / 4, 256, 0, stream>>>(y, d_in[4], d_in[5], h2, flags);
      gemm_bt<32, 64, 1, 0><<<dim3(Nc / 64, S / 32), 256, 0, stream>>>(
          h2, D_MODEL, w1T, D_MODEL, D_MODEL,
          d_in[11], 0, nullptr, nullptr, gbuf, Nc, flags, 11, 0, 1,
          nullptr, nullptr, nullptr);
      gemm_bt<32, 32, 3, 0><<<dim3(16, S / 32), 256, 0, stream>>>(
          gbuf, Nc, w2T, D_FFN, Nc, d_in[13], 0,
          nullptr, y, nullptr, D_MODEL, flags, 13, 0, 1,
          nullptr, nullptr, nullptr);
      gemm_bt<32, 64, 1, 0><<<dim3(Nc / 64, S / 32), 256, 0, stream>>>(
          h2, D_MODEL, w1T + (size_t)Nc * D_MODEL, D_MODEL, D_MODEL,
          d_in[11], Nc, nullptr, nullptr, gbuf, Nc, flags, 11, 0, 1,
          nullptr, nullptr, nullptr);
      gemm_bt<32, 32, 4, 0><<<dim3(16, S / 32), 256, 0, stream>>>(
          gbuf, Nc, w2T + (size_t)Nc, D_FFN, Nc, d_in[13], 0,
          nullptr, y, (ushort_t*)d_out, D_MODEL, flags, 13, 0, 0,
          nullptr, nullptr, nullptr);
    }
  } else {
    // fallback: round-6 proven path
    int P;
    if      (ws_size >= 12ull * MB + 4096) P = 1;
    else if (ws_size >=  8ull * MB + 4096) P = 2;
    else                                   P = 4;
    const int Nc = D_FFN / P;
    const size_t gbuf_bytes = (size_t)S * Nc * 2;
    const size_t qkv_bytes  = 3 * sD * 2;
    const size_t fo = 4ull * sD + gbuf_bytes;
    const size_t flags_pos = (qkv_bytes > fo ? qkv_bytes : fo);

    ushort_t* qkv  = (ushort_t*)ws;
    float*    y    = (float*)ws;
    ushort_t* gbuf = (ushort_t*)(ws + 4 * sD);
    int*      flags = (int*)(ws + flags_pos);

    detect_all<<<14, 256, 0, stream>>>(da, flags, nullptr, nullptr, 0);
    ln1_kernel<<<S / 4, 256, 0, stream>>>(d_in[0], d_in[2], d_in[3], h1, flags);
    gemm_nn<128, 128, 0><<<dim3((3 * D_MODEL) / 128, S / 128), 256, 0, stream>>>(
        h1, D_MODEL, D_MODEL, d_in[6], 3 * D_MODEL, 0, 0, d_in[7], 0,
        nullptr, nullptr, qkv, 3 * D_MODEL, flags, 6, 7, 0, 1);
    attn_kernel<<<(S * N_HEADS) / 4, 256, 0, stream>>>(qkv, attnb, S);
    gemm_nn<64, 64, 2><<<dim3(D_MODEL / 64, S / 64), 256, 0, stream>>>(
        attnb, D_MODEL, D_MODEL, d_in[8], D_MODEL, 0, 0, d_in[9], 0,
        d_in[0], y, nullptr, D_MODEL, flags, 8, 9, 0, 1);
    ln2_kernel<<<S / 4, 256, 0, stream>>>(y, d_in[4], d_in[5], h2, flags);
    for (int p = 0; p < P; ++p) {
      if (Nc >= 1024) {
        gemm_nn<128, 128, 1><<<dim3(Nc / 128, S / 128), 256, 0, stream>>>(
            h2, D_MODEL, D_MODEL, d_in[10], D_FFN, 0, p * Nc, d_in[11], p * Nc,
            nullptr, nullptr, gbuf, Nc, flags, 10, 11, 0, 1);
      } else {
        gemm_nn<64, 64, 1><<<dim3(Nc / 64, S / 64), 256, 0, stream>>>(
            h2, D_MODEL, D_MODEL, d_in[10], D_FFN, 0, p * Nc, d_in[11], p * Nc,
            nullptr, nullptr, gbuf, Nc, flags, 10, 11, 0, 1);
      }
      gemm_nn<64, 64, 3><<<dim3(D_MODEL / 64, S / 64), 256, 0, stream>>>(
          gbuf, Nc, Nc, d_in[12], D_MODEL, p * Nc, 0, d_in[13], 0,
          nullptr, y, nullptr, D_MODEL, flags, 12, 13, 0, p == 0 ? 1 : 0);
    }
    convert_kernel<<<(int)((sD + 255) / 256), 256, 0, stream>>>(y, d_out, flags, (int)sD);
  }
}

// Round 9
// 180.197 us; speedup vs baseline: 1.9348x; 1.0416x over previous
//
#include <hip/hip_runtime.h>
#include <math.h>

typedef float f32x4 __attribute__((ext_vector_type(4)));
typedef short s16x8 __attribute__((ext_vector_type(8)));
typedef unsigned short u16x8 __attribute__((ext_vector_type(8)));
typedef unsigned short ushort_t;
typedef unsigned int uint_t;

#define D_MODEL 512
#define N_HEADS 8
#define HEAD_D  64
#define D_FFN   2048

__device__ __forceinline__ float bf2f(unsigned short u) {
  union { unsigned int i; float f; } c; c.i = ((unsigned int)u) << 16; return c.f;
}
__device__ __forceinline__ unsigned short f2bf(float f) {
  union { float f; unsigned int i; } c; c.f = f;
  unsigned int x = c.i;
  return (unsigned short)((x + 0x7FFFu + ((x >> 16) & 1u)) >> 16);
}
__device__ __forceinline__ float ldx(const void* p, size_t i, int f) {
  return f ? ((const float*)p)[i] : bf2f(((const ushort_t*)p)[i]);
}

// ------------------------------------------------- fused dtype detector
// One tiny upfront kernel; every consumer pays a single scalar flags[] load.
// (R1/R2 lesson: per-block inline probes cost ~13 µs of tail latency.
//  R6/R7 lesson: LN2 algebraic fold into gemm3 was net-negative — it turned
//  the 1-pass ln2 into 32x-replayed f32 A-traffic. Keep ln2 as a dispatch.)
struct DetectArgs { const void* p[14]; int n[14]; };

__global__ __launch_bounds__(256)
void detect_all(DetectArgs a, int* __restrict__ flags) {
  __shared__ int cnt[2];
  const int b = blockIdx.x;
  const int t = threadIdx.x;
  if (b == 1) { if (t == 0) flags[1] = 0; return; }
  if (t == 0) { cnt[0] = 0; cnt[1] = 0; }
  __syncthreads();
  const int n_u32 = a.n[b] >> 1;
  const int sample = n_u32 < 256 ? n_u32 : 256;
  if (t < sample) {
    uint_t u = ((const uint_t*)a.p[b])[t];
    if (u != 0u) {
      atomicAdd(&cnt[0], 1);
      int e = (u >> 7) & 0xFF;
      if (e >= 0x70 && e <= 0x83) atomicAdd(&cnt[1], 1);
    }
  }
  __syncthreads();
  if (t == 0) flags[b] = (cnt[0] >= 32 && cnt[1] * 4 <= cnt[0]) ? 1 : 0;
}

// ------------------------------------------------- prep: weight convert+transpose AND ln1
// Independent work merged into one launch (flags-based: no per-block probes).
struct WDesc { const void* src; ushort_t* dst; int Kd, Nd, flag, tile0; };

__global__ __launch_bounds__(256)
void prep_kernel(WDesc w0, WDesc w1, WDesc w2, WDesc w3, int nconv,
                 const void* __restrict__ x, const void* __restrict__ g,
                 const void* __restrict__ b, ushort_t* __restrict__ h1,
                 const int* __restrict__ flags) {
  __shared__ ushort_t tile[32][33];
  const int blk = blockIdx.x;
  if (blk >= nconv) {
    // ----- ln1 path (4 rows per block)
    const int fx = flags[0], fg = flags[2], fb = flags[3];
    const int row = (blk - nconv) * 4 + (threadIdx.x >> 6);
    const int lane = threadIdx.x & 63;
    float v[8], sum = 0.f, sq = 0.f;
#pragma unroll
    for (int i = 0; i < 8; ++i) {
      v[i] = ldx(x, (size_t)row * D_MODEL + lane * 8 + i, fx);
      sum += v[i]; sq += v[i] * v[i];
    }
#pragma unroll
    for (int o = 32; o > 0; o >>= 1) { sum += __shfl_xor(sum, o); sq += __shfl_xor(sq, o); }
    const float mu = sum * (1.0f / D_MODEL);
    const float var = sq * (1.0f / D_MODEL) - mu * mu;
    const float rstd = rsqrtf(var + 1e-5f);
#pragma unroll
    for (int i = 0; i < 8; ++i) {
      int c = lane * 8 + i;
      h1[(size_t)row * D_MODEL + c] =
          f2bf((v[i] - mu) * rstd * ldx(g, c, fg) + ldx(b, c, fb));
    }
    return;
  }
  // ----- weight convert+transpose path
  WDesc d = (blk < w1.tile0) ? w0 : (blk < w2.tile0) ? w1 : (blk < w3.tile0) ? w2 : w3;
  const int lt = blk - d.tile0;
  const int tn = d.Nd / 32;
  const int bk = lt / tn, bn = lt % tn;
  const int f = flags[d.flag];
  const int tx = threadIdx.x & 31, ty = threadIdx.x >> 5;
#pragma unroll
  for (int r = 0; r < 4; ++r) {
    int k = bk * 32 + ty * 4 + r;
    tile[ty * 4 + r][tx] = f2bf(ldx(d.src, (size_t)k * d.Nd + bn * 32 + tx, f));
  }
  __syncthreads();
#pragma unroll
  for (int r = 0; r < 4; ++r) {
    int n = bn * 32 + ty * 4 + r;
    d.dst[(size_t)n * d.Kd + bk * 32 + tx] = tile[tx][ty * 4 + r];
  }
}

// ------------------------------------------------- LN kernels
__global__ __launch_bounds__(256)
void ln1_kernel(const void* __restrict__ x, const void* __restrict__ g,
                const void* __restrict__ b, ushort_t* __restrict__ out,
                const int* __restrict__ flags) {
  const int fx = flags[0], fg = flags[2], fb = flags[3];
  const int row = blockIdx.x * 4 + (threadIdx.x >> 6);
  const int lane = threadIdx.x & 63;
  float v[8], sum = 0.f, sq = 0.f;
#pragma unroll
  for (int i = 0; i < 8; ++i) {
    v[i] = ldx(x, (size_t)row * D_MODEL + lane * 8 + i, fx);
    sum += v[i]; sq += v[i] * v[i];
  }
#pragma unroll
  for (int o = 32; o > 0; o >>= 1) { sum += __shfl_xor(sum, o); sq += __shfl_xor(sq, o); }
  const float mu = sum * (1.0f / D_MODEL);
  const float var = sq * (1.0f / D_MODEL) - mu * mu;
  const float rstd = rsqrtf(var + 1e-5f);
#pragma unroll
  for (int i = 0; i < 8; ++i) {
    int c = lane * 8 + i;
    out[(size_t)row * D_MODEL + c] =
        f2bf((v[i] - mu) * rstd * ldx(g, c, fg) + ldx(b, c, fb));
  }
}

__global__ __launch_bounds__(256)
void ln2_kernel(const float* __restrict__ y, const void* __restrict__ g,
                const void* __restrict__ b, ushort_t* __restrict__ out,
                const int* __restrict__ flags) {
  const int fg = flags[4], fb = flags[5];
  const int row = blockIdx.x * 4 + (threadIdx.x >> 6);
  const int lane = threadIdx.x & 63;
  float v[8], sum = 0.f, sq = 0.f;
#pragma unroll
  for (int i = 0; i < 8; ++i) {
    v[i] = y[(size_t)row * D_MODEL + lane * 8 + i];
    sum += v[i]; sq += v[i] * v[i];
  }
#pragma unroll
  for (int o = 32; o > 0; o >>= 1) { sum += __shfl_xor(sum, o); sq += __shfl_xor(sq, o); }
  const float mu = sum * (1.0f / D_MODEL);
  const float var = sq * (1.0f / D_MODEL) - mu * mu;
  const float rstd = rsqrtf(var + 1e-5f);
#pragma unroll
  for (int i = 0; i < 8; ++i) {
    int c = lane * 8 + i;
    out[(size_t)row * D_MODEL + c] =
        f2bf((v[i] - mu) * rstd * ldx(g, c, fg) + ldx(b, c, fb));
  }
}

// ------------------------------------------------- pipelined MFMA GEMM, BK=64
// R5 write-early dbuf (proven, 180.8 µs): loads issued one full K-step ahead
// of their swrite; swizzled granules ((k>>3)^(row&7)); ONE barrier per
// K-step; 24 KB LDS -> 6 blocks/CU for 32x64.
// R8 adds: epilogue-dependency PREFETCH — flags, bias row, and residual/yacc
// values are loaded BEFORE the K-loop (addresses known at entry, data stable),
// so the whole K-loop covers their latency instead of a serial post-MFMA tail.
// EPI: 0 = +bias -> bf16            1 = gelu(+bias) -> bf16
//      2 = y[off] = v+bias+res      3 = y[off] += v (+bias if addb)
//      4 = out[off] = y[off] + v (+bias if addb; dtype per flags[ires])
template <int BM, int BN, int EPI>
__global__ __launch_bounds__(256)
void gemm_bt(const ushort_t* __restrict__ A, int lda,
             const ushort_t* __restrict__ BT, int ldb, int K,
             const void* __restrict__ bias, int bias_off,
             const void* __restrict__ res,
             float* __restrict__ yacc,
             ushort_t* __restrict__ out_bf, int ldo,
             const int* __restrict__ flags, int ibias, int ires, int addb) {
  constexpr int BK = 64;
  constexpr int FM = BM / 32, FN = BN / 32;
  constexpr int AG = BM / 32, BG = BN / 32;   // staging groups of 32 rows
  __shared__ __attribute__((aligned(16))) ushort_t As[2][BM][64];
  __shared__ __attribute__((aligned(16))) ushort_t Bs[2][BN][64];

  const int t = threadIdx.x;
  const int lane = t & 63, wave = t >> 6;
  const int wm = wave >> 1, wn = wave & 1;
  const int q = lane >> 4, lm = lane & 15;
  const int m0 = blockIdx.y * BM, n0 = blockIdx.x * BN;
  const int srow = t >> 3, sslot = t & 7;   // 32 rows x 8 granules per pass
  const int wslot = (sslot ^ (srow & 7)) * 8;  // swizzled write column
  const int xorg = lm & 7;                   // fragment-read swizzle

  f32x4 acc[FM][FN];
#pragma unroll
  for (int i = 0; i < FM; ++i)
#pragma unroll
    for (int j = 0; j < FN; ++j) acc[i][j] = (f32x4)(0.0f);

  // ---- epilogue-dependency prefetch (covered by the whole K-loop)
  const int fbias = flags[ibias];
  int fres = 0;
  if constexpr (EPI == 2 || EPI == 4) fres = flags[ires];
  float bbp[FN];
#pragma unroll
  for (int j = 0; j < FN; ++j) {
    if (EPI <= 2 || addb)
      bbp[j] = ldx(bias, bias_off + n0 + wn * (BN / 2) + j * 16 + lm, fbias);
    else bbp[j] = 0.0f;
  }
  float pre[FM][FN][4];
  if constexpr (EPI == 2 || EPI == 4) {
#pragma unroll
    for (int i = 0; i < FM; ++i)
#pragma unroll
      for (int j = 0; j < FN; ++j) {
        const int colg = n0 + wn * (BN / 2) + j * 16 + lm;
#pragma unroll
        for (int r = 0; r < 4; ++r) {
          const int rowg = m0 + wm * (BM / 2) + i * 16 + q * 4 + r;
          const size_t off = (size_t)rowg * ldo + colg;
          if constexpr (EPI == 2) pre[i][j][r] = ldx(res, off, fres);
          else                    pre[i][j][r] = yacc[off];
        }
      }
  }

  u16x8 av[AG], bv[BG];

  auto gload = [&](int k0) {
#pragma unroll
    for (int r = 0; r < AG; ++r)
      av[r] = *(const u16x8*)(A + (size_t)(m0 + r * 32 + srow) * lda + k0 + sslot * 8);
#pragma unroll
    for (int r = 0; r < BG; ++r)
      bv[r] = *(const u16x8*)(BT + (size_t)(n0 + r * 32 + srow) * ldb + k0 + sslot * 8);
  };
  auto swrite = [&](int buf) {
#pragma unroll
    for (int r = 0; r < AG; ++r) *(u16x8*)&As[buf][r * 32 + srow][wslot] = av[r];
#pragma unroll
    for (int r = 0; r < BG; ++r) *(u16x8*)&Bs[buf][r * 32 + srow][wslot] = bv[r];
  };
  auto frag_mfma = [&](int buf, int kh) {
    s16x8 af[FM], bf[FN];
    const int rcol = ((kh * 4 + q) ^ xorg) * 8;   // swizzled read column
#pragma unroll
    for (int i = 0; i < FM; ++i)
      af[i] = *(const s16x8*)&As[buf][wm * (BM / 2) + i * 16 + lm][rcol];
#pragma unroll
    for (int j = 0; j < FN; ++j)
      bf[j] = *(const s16x8*)&Bs[buf][wn * (BN / 2) + j * 16 + lm][rcol];
#pragma unroll
    for (int i = 0; i < FM; ++i)
#pragma unroll
      for (int j = 0; j < FN; ++j)
        acc[i][j] = __builtin_amdgcn_mfma_f32_16x16x32_bf16(af[i], bf[j], acc[i][j], 0, 0, 0);
  };

  const int NT = K / BK;
  gload(0);
  swrite(0);            // exposed vmcnt once (prologue only)
  __syncthreads();
  gload(BK);            // tile 1 in flight across the whole first K-step
  int buf = 0;
  for (int kt = 1; kt < NT; ++kt) {
    swrite(buf ^ 1);    // stage tile kt (issued last iteration: latency covered)
    if (kt + 1 < NT) gload((kt + 1) * BK);   // issue tile kt+1
    frag_mfma(buf, 0);  // compute tile kt-1
    frag_mfma(buf, 1);
    __syncthreads();    // ONE barrier per K-step
    buf ^= 1;
  }
  frag_mfma(buf, 0);    // compute tile NT-1
  frag_mfma(buf, 1);

#pragma unroll
  for (int i = 0; i < FM; ++i) {
#pragma unroll
    for (int j = 0; j < FN; ++j) {
      const int colg = n0 + wn * (BN / 2) + j * 16 + lm;
      const float bb = bbp[j];
#pragma unroll
      for (int r = 0; r < 4; ++r) {
        const int rowg = m0 + wm * (BM / 2) + i * 16 + q * 4 + r;
        float v = acc[i][j][r] + bb;
        const size_t off = (size_t)rowg * ldo + colg;
        if constexpr (EPI == 0) {
          out_bf[off] = f2bf(v);
        } else if constexpr (EPI == 1) {
          out_bf[off] = f2bf(0.5f * v * (1.0f + erff(v * 0.70710678f)));
        } else if constexpr (EPI == 2) {
          yacc[off] = v + pre[i][j][r];
        } else if constexpr (EPI == 3) {
          yacc[off] += v;
        } else {
          float fin = pre[i][j][r] + v;
          if (fres) ((float*)(void*)out_bf)[off] = fin;
          else      out_bf[off] = f2bf(fin);
        }
      }
    }
  }
}

// ------------------------------------------------- legacy GEMM (fallback path, r6-proven)
template <int BM, int BN, int EPI>
__global__ __launch_bounds__(256)
void gemm_nn(const ushort_t* __restrict__ A, int lda, int K,
             const void* __restrict__ B, int ldb, int brow0, int bcol0,
             const void* __restrict__ bias, int bias_off,
             const void* __restrict__ res,
             float* __restrict__ yacc,
             ushort_t* __restrict__ out_bf, int ldo,
             const int* __restrict__ flags, int iB, int ibias, int ires, int addb) {
  constexpr int BK = 32;
  constexpr int FM = BM / 32, FN = BN / 32;
  __shared__ __attribute__((aligned(16))) ushort_t As[BM][40];
  __shared__ ushort_t Bs[BK][BN + 2];
  const int t = threadIdx.x;
  const int lane = t & 63, wave = t >> 6;
  const int wm = wave >> 1, wn = wave & 1;
  const int m0 = blockIdx.y * BM, n0 = blockIdx.x * BN;
  const int fB = flags[iB], fbias = flags[ibias];
  f32x4 acc[FM][FN];
#pragma unroll
  for (int i = 0; i < FM; ++i)
#pragma unroll
    for (int j = 0; j < FN; ++j) acc[i][j] = (f32x4)(0.0f);
  const int q = lane >> 4, lm = lane & 15;
  const int arow_s = t >> 2, aslot = t & 3;
  for (int k0 = 0; k0 < K; k0 += BK) {
    __syncthreads();
#pragma unroll
    for (int r = 0; r < BM / 64; ++r) {
      int row = r * 64 + arow_s;
      *(u16x8*)&As[row][aslot * 8] =
          *(const u16x8*)(A + (size_t)(m0 + row) * lda + k0 + aslot * 8);
    }
#pragma unroll
    for (int e = 0; e < (BK * BN) / 256; ++e) {
      int id = e * 256 + t;
      int k = id / BN, n = id % BN;
      Bs[k][n] = f2bf(ldx(B, (size_t)(brow0 + k0 + k) * ldb + bcol0 + n0 + n, fB));
    }
    __syncthreads();
    s16x8 af[FM], bf[FN];
#pragma unroll
    for (int i = 0; i < FM; ++i)
      af[i] = *(const s16x8*)&As[wm * (BM / 2) + i * 16 + lm][q * 8];
#pragma unroll
    for (int j = 0; j < FN; ++j) {
      int nl = wn * (BN / 2) + j * 16 + lm;
      u16x8 tmp;
#pragma unroll
      for (int f = 0; f < 8; ++f) tmp[f] = Bs[q * 8 + f][nl];
      bf[j] = __builtin_bit_cast(s16x8, tmp);
    }
#pragma unroll
    for (int i = 0; i < FM; ++i)
#pragma unroll
      for (int j = 0; j < FN; ++j)
        acc[i][j] = __builtin_amdgcn_mfma_f32_16x16x32_bf16(af[i], bf[j], acc[i][j], 0, 0, 0);
  }
#pragma unroll
  for (int i = 0; i < FM; ++i) {
#pragma unroll
    for (int j = 0; j < FN; ++j) {
      const int col = wn * (BN / 2) + j * 16 + lm;
      float bb = 0.0f;
      if (EPI != 3 || addb) bb = ldx(bias, bias_off + n0 + col, fbias);
#pragma unroll
      for (int r = 0; r < 4; ++r) {
        const int rowg = m0 + wm * (BM / 2) + i * 16 + q * 4 + r;
        float v = acc[i][j][r] + bb;
        if constexpr (EPI == 0) {
          out_bf[(size_t)rowg * ldo + n0 + col] = f2bf(v);
        } else if constexpr (EPI == 1) {
          out_bf[(size_t)rowg * ldo + n0 + col] =
              f2bf(0.5f * v * (1.0f + erff(v * 0.70710678f)));
        } else if constexpr (EPI == 2) {
          const size_t off = (size_t)rowg * D_MODEL + n0 + col;
          yacc[off] = v + ldx(res, off, flags[ires]);
        } else {
          const size_t off = (size_t)rowg * D_MODEL + n0 + col;
          yacc[off] += v;
        }
      }
    }
  }
}

// ------------------------------------------------- attention (r14 coalesced-K)
// XCD-aware block swizzle (T1): neutral-vs-R0 at S=2048 but mechanistically
// sound (one head's 512 KB K/V slice per XCD L2) and harmless — kept.
__device__ __forceinline__ int key_index(int s, int j, int S) {
  int p;
  if (j < 64)       p = s + j - 32;
  else if (j < 102) p = s + (j - 83) * 64;
  else              p = ((j - 102) * (S - 1)) / 25;
  return min(max(p, 0), S - 1);
}

__global__ __launch_bounds__(256, 4)
void attn_kernel(const ushort_t* __restrict__ qkv, ushort_t* __restrict__ out, int S) {
  const int wave = threadIdx.x >> 6, lane = threadIdx.x & 63;
  const int nb = gridDim.x;
  int bid = blockIdx.x;
  if ((nb & 7) == 0) bid = (bid & 7) * (nb >> 3) + (bid >> 3);  // XCD swizzle (bijective)
  const int pair = bid * 4 + wave;          // pair = h*S + s
  const int h = pair / S;
  const int s = pair - h * S;
  const int g = lane >> 3, d8 = (lane & 7) * 8;

  int koff[16];
#pragma unroll
  for (int r = 0; r < 16; ++r)
    koff[r] = key_index(s, r * 8 + g, S) * (3 * D_MODEL);

  u16x8 qv8 = *(const u16x8*)(qkv + (size_t)s * (3 * D_MODEL) + h * HEAD_D + d8);
  float qf[8];
#pragma unroll
  for (int e = 0; e < 8; ++e) qf[e] = bf2f(qv8[e]);

  const ushort_t* kbase = qkv + D_MODEL + h * HEAD_D + d8;
  float pr[16];
  {
    u16x8 kv[8];
#pragma unroll
    for (int r = 0; r < 8; ++r) kv[r] = *(const u16x8*)(kbase + koff[r]);
#pragma unroll
    for (int r = 0; r < 16; ++r) {
      u16x8 cur = kv[r & 7];
      if (r < 8) kv[r & 7] = *(const u16x8*)(kbase + koff[r + 8]);
      float d = 0.f;
#pragma unroll
      for (int e = 0; e < 8; ++e) d += qf[e] * bf2f(cur[e]);
      d += __shfl_xor(d, 1);
      d += __shfl_xor(d, 2);
      d += __shfl_xor(d, 4);
      pr[r] = d * 0.125f;
    }
  }

  float mx = pr[0];
#pragma unroll
  for (int r = 1; r < 16; ++r) mx = fmaxf(mx, pr[r]);
#pragma unroll
  for (int m = 8; m <= 32; m <<= 1) mx = fmaxf(mx, __shfl_xor(mx, m));
  float sm = 0.f;
#pragma unroll
  for (int r = 0; r < 16; ++r) { pr[r] = __expf(pr[r] - mx); sm += pr[r]; }
#pragma unroll
  for (int m = 8; m <= 32; m <<= 1) sm += __shfl_xor(sm, m);
  const float inv = 1.0f / sm;

  const ushort_t* vbase = qkv + 2 * D_MODEL + h * HEAD_D + d8;
  float oacc[8];
#pragma unroll
  for (int e = 0; e < 8; ++e) oacc[e] = 0.f;
  {
    u16x8 vv[8];
#pragma unroll
    for (int r = 0; r < 8; ++r) vv[r] = *(const u16x8*)(vbase + koff[r]);
#pragma unroll
    for (int r = 0; r < 16; ++r) {
      u16x8 cv = vv[r & 7];
      float cp = pr[r] * inv;
      if (r < 8) vv[r & 7] = *(const u16x8*)(vbase + koff[r + 8]);
#pragma unroll
      for (int e = 0; e < 8; ++e) oacc[e] += cp * bf2f(cv[e]);
    }
  }
#pragma unroll
  for (int m = 8; m <= 32; m <<= 1)
#pragma unroll
    for (int e = 0; e < 8; ++e) oacc[e] += __shfl_xor(oacc[e], m);

  if (lane < 8) {
    u16x8 ov;
#pragma unroll
    for (int e = 0; e < 8; ++e) ov[e] = f2bf(oacc[e]);
    *(u16x8*)(out + (size_t)s * D_MODEL + h * HEAD_D + d8) = ov;
  }
}

// ------------------------------------------------- final convert (fallback only)
__global__ __launch_bounds__(256)
void convert_kernel(const float* __restrict__ y, void* __restrict__ out,
                    const int* __restrict__ flags, int n) {
  const int fout = flags[0];
  int i = blockIdx.x * 256 + threadIdx.x;
  if (i < n) {
    float v = y[i];
    if (fout) ((float*)out)[i] = v;
    else      ((ushort_t*)out)[i] = f2bf(v);
  }
}

// ------------------------------------------------- launch
extern "C" void kernel_launch(void* const* d_in, const int* in_sizes, int n_in,
                              void* d_out, int out_size, void* d_ws, size_t ws_size,
                              hipStream_t stream) {
  const int S = in_sizes[0] / D_MODEL;    // 2048
  const size_t sD = (size_t)S * D_MODEL;
  char* ws = (char*)d_ws;

  DetectArgs da;
  for (int i = 0; i < 14; ++i) { da.p[i] = d_in[i]; da.n[i] = in_sizes[i]; }

  ushort_t* h1    = (ushort_t*)d_out;
  ushort_t* attnb = (ushort_t*)d_out;
  ushort_t* h2    = (ushort_t*)d_out;

  const size_t MB = 1024 * 1024;
  if (ws_size >= 12 * MB + 64) {
    const int P  = (ws_size >= 20 * MB) ? 1 : 2;
    const int Nc = D_FFN / P;
    char* wbase = ws + (P == 1 ? 12 : 6) * MB;

    ushort_t* qkv   = (ushort_t*)ws;                       // [0,6M)
    float*    y     = (float*)ws;                          // [0,4M) after qkv dies
    ushort_t* gbuf  = (ushort_t*)(ws + 4 * MB);            // S*Nc bf16 (4 or 8 MB)
    ushort_t* wqkvT = (ushort_t*)wbase;                    // 1.5 MB
    ushort_t* woT   = (ushort_t*)(wbase + 1 * MB + 512 * 1024);  // 0.5 MB
    ushort_t* w1T   = (ushort_t*)(wbase + 2 * MB);         // 2 MB
    ushort_t* w2T   = (ushort_t*)(wbase + 4 * MB);         // 2 MB
    int*      flags = (int*)(wbase + 6 * MB);

    detect_all<<<14, 256, 0, stream>>>(da, flags);

    WDesc dq  = { d_in[6],  wqkvT, D_MODEL, 3 * D_MODEL, 6,  0 };
    WDesc dwo = { d_in[8],  woT,   D_MODEL, D_MODEL,     8,  768 };
    WDesc dw1 = { d_in[10], w1T,   D_MODEL, D_FFN,       10, 1024 };
    WDesc dw2 = { d_in[12], w2T,   D_FFN,   D_MODEL,     12, 2048 };

    // K2: weight convert (3072 blocks) + ln1 (S/4 blocks), flags-based
    prep_kernel<<<3072 + S / 4, 256, 0, stream>>>(
        dq, dwo, dw1, dw2, 3072, d_in[0], d_in[2], d_in[3], h1, flags);

    // GEMM1: h1 @ wqkv + bqkv -> qkv  (32x64, 1536 blocks, 6/CU)
    gemm_bt<32, 64, 0><<<dim3(24, S / 32), 256, 0, stream>>>(
        h1, D_MODEL, wqkvT, D_MODEL, D_MODEL, d_in[7], 0,
        nullptr, nullptr, qkv, 3 * D_MODEL, flags, 7, 0, 1);

    attn_kernel<<<(S * N_HEADS) / 4, 256, 0, stream>>>(qkv, attnb, S);

    // GEMM2: attnb @ wo + bo + x -> y (32x32, 1024 blocks, 4/CU)
    gemm_bt<32, 32, 2><<<dim3(16, S / 32), 256, 0, stream>>>(
        attnb, D_MODEL, woT, D_MODEL, D_MODEL, d_in[9], 0,
        d_in[0], y, nullptr, D_MODEL, flags, 9, 0, 1);

    ln2_kernel<<<S / 4, 256, 0, stream>>>(y, d_in[4], d_in[5], h2, flags);

    if (P == 1) {
      // GEMM3: h2 @ w1 + b1 -> gelu -> gbuf  (32x64, 2048 blocks, 8/CU)
      gemm_bt<32, 64, 1><<<dim3(D_FFN / 64, S / 32), 256, 0, stream>>>(
          h2, D_MODEL, w1T, D_MODEL, D_MODEL,
          d_in[11], 0, nullptr, nullptr, gbuf, D_FFN, flags, 11, 0, 1);
      // GEMM4: out = y + gbuf @ w2 + b2  (K=2048; 32x32, 1024 blocks, 4/CU)
      gemm_bt<32, 32, 4><<<dim3(16, S / 32), 256, 0, stream>>>(
          gbuf, D_FFN, w2T, D_FFN, D_FFN, d_in[13], 0,
          nullptr, y, (ushort_t*)d_out, D_MODEL, flags, 13, 0, 1);
    } else {
      gemm_bt<32, 64, 1><<<dim3(Nc / 64, S / 32), 256, 0, stream>>>(
          h2, D_MODEL, w1T, D_MODEL, D_MODEL,
          d_in[11], 0, nullptr, nullptr, gbuf, Nc, flags, 11, 0, 1);
      gemm_bt<32, 32, 3><<<dim3(16, S / 32), 256, 0, stream>>>(
          gbuf, Nc, w2T, D_FFN, Nc, d_in[13], 0,
          nullptr, y, nullptr, D_MODEL, flags, 13, 0, 1);
      gemm_bt<32, 64, 1><<<dim3(Nc / 64, S / 32), 256, 0, stream>>>(
          h2, D_MODEL, w1T + (size_t)Nc * D_MODEL, D_MODEL, D_MODEL,
          d_in[11], Nc, nullptr, nullptr, gbuf, Nc, flags, 11, 0, 1);
      gemm_bt<32, 32, 4><<<dim3(16, S / 32), 256, 0, stream>>>(
          gbuf, Nc, w2T + (size_t)Nc, D_FFN, Nc, d_in[13], 0,
          nullptr, y, (ushort_t*)d_out, D_MODEL, flags, 13, 0, 0);
    }
  } else {
    // fallback: round-6 proven path
    int P;
    if      (ws_size >= 12ull * MB + 4096) P = 1;
    else if (ws_size >=  8ull * MB + 4096) P = 2;
    else                                   P = 4;
    const int Nc = D_FFN / P;
    const size_t gbuf_bytes = (size_t)S * Nc * 2;
    const size_t qkv_bytes  = 3 * sD * 2;
    const size_t fo = 4ull * sD + gbuf_bytes;
    const size_t flags_pos = (qkv_bytes > fo ? qkv_bytes : fo);

    ushort_t* qkv  = (ushort_t*)ws;
    float*    y    = (float*)ws;
    ushort_t* gbuf = (ushort_t*)(ws + 4 * sD);
    int*      flags = (int*)(ws + flags_pos);

    detect_all<<<14, 256, 0, stream>>>(da, flags);
    ln1_kernel<<<S / 4, 256, 0, stream>>>(d_in[0], d_in[2], d_in[3], h1, flags);
    gemm_nn<128, 128, 0><<<dim3((3 * D_MODEL) / 128, S / 128), 256, 0, stream>>>(
        h1, D_MODEL, D_MODEL, d_in[6], 3 * D_MODEL, 0, 0, d_in[7], 0,
        nullptr, nullptr, qkv, 3 * D_MODEL, flags, 6, 7, 0, 1);
    attn_kernel<<<(S * N_HEADS) / 4, 256, 0, stream>>>(qkv, attnb, S);
    gemm_nn<64, 64, 2><<<dim3(D_MODEL / 64, S / 64), 256, 0, stream>>>(
        attnb, D_MODEL, D_MODEL, d_in[8], D_MODEL, 0, 0, d_in[9], 0,
        d_in[0], y, nullptr, D_MODEL, flags, 8, 9, 0, 1);
    ln2_kernel<<<S / 4, 256, 0, stream>>>(y, d_in[4], d_in[5], h2, flags);
    for (int p = 0; p < P; ++p) {
      if (Nc >= 1024) {
        gemm_nn<128, 128, 1><<<dim3(Nc / 128, S / 128), 256, 0, stream>>>(
            h2, D_MODEL, D_MODEL, d_in[10], D_FFN, 0, p * Nc, d_in[11], p * Nc,
            nullptr, nullptr, gbuf, Nc, flags, 10, 11, 0, 1);
      } else {
        gemm_nn<64, 64, 1><<<dim3(Nc / 64, S / 64), 256, 0, stream>>>(
            h2, D_MODEL, D_MODEL, d_in[10], D_FFN, 0, p * Nc, d_in[11], p * Nc,
            nullptr, nullptr, gbuf, Nc, flags, 10, 11, 0, 1);
      }
      gemm_nn<64, 64, 3><<<dim3(D_MODEL / 64, S / 64), 256, 0, stream>>>(
          gbuf, Nc, Nc, d_in[12], D_MODEL, p * Nc, 0, d_in[13], 0,
          nullptr, y, nullptr, D_MODEL, flags, 12, 13, 0, p == 0 ? 1 : 0);
    }
    convert_kernel<<<(int)((sD + 255) / 256), 256, 0, stream>>>(y, d_out, flags, (int)sD);
  }
}